// Round 1
// baseline (1030.290 us; speedup 1.0000x reference)
//
#include <hip/hip_runtime.h>

// ---------------- problem constants ----------------
#define H 1024
#define W 1024
#define HW (H*W)
#define NB 8            // batch
#define NIMG 16         // gt batch (0..7) + pred-fg batch (8..15)
#define BORDER 25
#define KLEN 51
#define PTW 128         // pooling tile width  (center)
#define PTH 32          // pooling tile height (center)

// Unnormalized Gaussian weights g[k] = exp(-(k-25)^2/200), k=0..50 (sigma=10).
__device__ __constant__ float GW[KLEN] = {
  0.04393693f, 0.05613476f, 0.07100535f, 0.08892162f, 0.11025053f,
  0.13533528f, 0.16447446f, 0.19789869f, 0.23574608f, 0.27803730f,
  0.32465247f, 0.37531110f, 0.42955736f, 0.48675226f, 0.54607442f,
  0.60653066f, 0.66697681f, 0.72614904f, 0.78270454f, 0.83527021f,
  0.88249690f, 0.92311635f, 0.95599748f, 0.98019867f, 0.99501248f,
  1.00000000f,
  0.99501248f, 0.98019867f, 0.95599748f, 0.92311635f, 0.88249690f,
  0.83527021f, 0.78270454f, 0.72614904f, 0.66697681f, 0.60653066f,
  0.54607442f, 0.48675226f, 0.42955736f, 0.37531110f, 0.32465247f,
  0.27803730f, 0.23574608f, 0.19789869f, 0.16447446f, 0.13533528f,
  0.11025053f, 0.08892162f, 0.07100535f, 0.05613476f, 0.04393693f
};

// 3-wide stage: dst[a] = OP(src[a-D], src[a], src[a+D]) over region rows[r0,r1) cols[c0,c1)
#define STAGE3(dst, src, OP, D, r0, r1, c0, c1)                              \
  { const int w_ = (c1)-(c0); const int n_ = ((r1)-(r0))*w_;                 \
    for (int i_ = tid; i_ < n_; i_ += 256) {                                 \
      int r_ = (r0) + i_/w_, c_ = (c0) + i_%w_; int a_ = r_*LW + c_;         \
      dst[a_] = OP(OP(src[a_-(D)], src[a_]), src[a_+(D)]);                   \
    } }

// Fused skeletonize kernel: (optional init skel) + NIT erode/open/update iterations.
// img state lives in LDS (l0), skel lives in registers across the launch.
template<int NIT, bool INIT>
__global__ __launch_bounds__(256)
void skel_kernel(const float* __restrict__ X, const float* __restrict__ pred,
                 const float* __restrict__ targ, float* __restrict__ Y,
                 float* __restrict__ S, int writeY)
{
  constexpr int HALO = 3*NIT;
  constexpr int LH = PTH + 2*HALO;
  constexpr int LW = PTW + 2*HALO;
  constexpr float FINF = __builtin_huge_valf();
  static_assert((PTH*PTW) % 256 == 0, "center mapping");
  __shared__ float l0[LH*LW];
  __shared__ float l1[LH*LW];

  const int img = blockIdx.z;
  const int gy0 = blockIdx.y*PTH - HALO;
  const int gx0 = blockIdx.x*PTW - HALO;
  const int tid = threadIdx.x;

  // ---- load image tile (+halo) into l0; out-of-image = +inf (min-pool identity)
  if constexpr (INIT) {
    for (int i = tid; i < LH*LW; i += 256) {
      int r = i/LW, c = i%LW;
      int gy = gy0+r, gx = gx0+c;
      float v = FINF;
      if (gy>=0 && gy<H && gx>=0 && gx<W) {
        int off = gy*W+gx;
        if (img < NB) v = targ[(size_t)img*HW + off];
        else {
          int b = img - NB;
          float p0 = pred[(size_t)(2*b  )*HW + off];
          float p1 = pred[(size_t)(2*b+1)*HW + off];
          v = 1.0f/(1.0f + expf(p0 - p1));   // softmax fg = sigmoid(p1-p0)
        }
      }
      l0[i] = v;
    }
  } else {
    const float* Xi = X + (size_t)img*HW;
    for (int i = tid; i < LH*LW; i += 256) {
      int r = i/LW, c = i%LW;
      int gy = gy0+r, gx = gx0+c;
      l0[i] = (gy>=0 && gy<H && gx>=0 && gx<W) ? Xi[gy*W+gx] : FINF;
    }
  }

  float sk[(PTH*PTW)/256];   // 16 skel values per thread (center 32x128)
  if constexpr (!INIT) {
    const float* Si = S + (size_t)img*HW;
    #pragma unroll
    for (int k = 0; k < 16; ++k) {
      int i = tid + 256*k;
      int r = i>>7, c = i&127;
      sk[k] = Si[(gy0+HALO+r)*W + (gx0+HALO+c)];
    }
  }
  __syncthreads();

  // ---- initial skeleton: sk = relu(X - dilate(erode(X)))
  if constexpr (INIT) {
    constexpr int MEI = HALO-1;
    STAGE3(l1, l0, fminf, 1, MEI-1, LH-MEI+1, MEI, LW-MEI);       // row-min of X
    __syncthreads();
    {  // e_i = col-min, masked to -inf outside image (staged in-place in l1)
      constexpr int r0 = MEI, r1 = LH-MEI, c0 = MEI, c1 = LW-MEI;
      constexpr int w = c1-c0, n = (r1-r0)*w, NJ = (n+255)/256;
      float stg[NJ];
      #pragma unroll
      for (int j = 0; j < NJ; ++j) {
        int i = tid + 256*j;
        if (i < n) {
          int r = r0 + i/w, c = c0 + i%w; int a = r*LW+c;
          float v = fminf(fminf(l1[a-LW], l1[a]), l1[a+LW]);
          int gy = gy0+r, gx = gx0+c;
          stg[j] = (gy>=0 && gy<H && gx>=0 && gx<W) ? v : -FINF;
        }
      }
      __syncthreads();
      #pragma unroll
      for (int j = 0; j < NJ; ++j) {
        int i = tid + 256*j;
        if (i < n) { int r = r0+i/w, c = c0+i%w; l1[r*LW+c] = stg[j]; }
      }
    }
    __syncthreads();
    {  // row-max of e_i (staged in-place in l1)
      constexpr int r0 = HALO-1, r1 = LH-HALO+1, c0 = HALO, c1 = LW-HALO;
      constexpr int w = c1-c0, n = (r1-r0)*w, NJ = (n+255)/256;
      float stg[NJ];
      #pragma unroll
      for (int j = 0; j < NJ; ++j) {
        int i = tid + 256*j;
        if (i < n) {
          int r = r0 + i/w, c = c0 + i%w; int a = r*LW+c;
          stg[j] = fmaxf(fmaxf(l1[a-1], l1[a]), l1[a+1]);
        }
      }
      __syncthreads();
      #pragma unroll
      for (int j = 0; j < NJ; ++j) {
        int i = tid + 256*j;
        if (i < n) { int r = r0+i/w, c = c0+i%w; l1[r*LW+c] = stg[j]; }
      }
    }
    __syncthreads();
    #pragma unroll
    for (int k = 0; k < 16; ++k) {   // o_i = col-max; sk = relu(X - o_i)
      int i = tid + 256*k;
      int r = HALO + (i>>7), c = HALO + (i&127);
      int a = r*LW + c;
      float o = fmaxf(fmaxf(l1[a-LW], l1[a]), l1[a+LW]);
      sk[k] = fmaxf(l0[a] - o, 0.0f);
    }
    __syncthreads();
  }

  // ---- NIT iterations: img=erode(img); delta=relu(img-open(img)); skel update
  #pragma unroll
  for (int it = 0; it < NIT; ++it) {
    const int me = 3*it + 1;          // margin of new img (e) after this erode
    constexpr int ME2 = HALO - 1;     // margin where e2 is needed (for o at center)

    STAGE3(l1, l0, fminf, 1,  me-1, LH-me+1, me, LW-me);    // row-min(img)
    __syncthreads();
    STAGE3(l0, l1, fminf, LW, me,   LH-me,   me, LW-me);    // e = col-min -> new img (l0)
    __syncthreads();
    STAGE3(l1, l0, fminf, 1,  ME2-1, LH-ME2+1, ME2, LW-ME2);// row-min(e)
    __syncthreads();
    {  // e2 = col-min, masked -inf outside image (staged in-place in l1)
      constexpr int r0 = ME2, r1 = LH-ME2, c0 = ME2, c1 = LW-ME2;
      constexpr int w = c1-c0, n = (r1-r0)*w, NJ = (n+255)/256;
      float stg[NJ];
      #pragma unroll
      for (int j = 0; j < NJ; ++j) {
        int i = tid + 256*j;
        if (i < n) {
          int r = r0 + i/w, c = c0 + i%w; int a = r*LW+c;
          float v = fminf(fminf(l1[a-LW], l1[a]), l1[a+LW]);
          int gy = gy0+r, gx = gx0+c;
          stg[j] = (gy>=0 && gy<H && gx>=0 && gx<W) ? v : -FINF;
        }
      }
      __syncthreads();
      #pragma unroll
      for (int j = 0; j < NJ; ++j) {
        int i = tid + 256*j;
        if (i < n) { int r = r0+i/w, c = c0+i%w; l1[r*LW+c] = stg[j]; }
      }
    }
    __syncthreads();
    {  // row-max(e2) (staged in-place in l1)
      constexpr int r0 = HALO-1, r1 = LH-HALO+1, c0 = HALO, c1 = LW-HALO;
      constexpr int w = c1-c0, n = (r1-r0)*w, NJ = (n+255)/256;
      float stg[NJ];
      #pragma unroll
      for (int j = 0; j < NJ; ++j) {
        int i = tid + 256*j;
        if (i < n) {
          int r = r0 + i/w, c = c0 + i%w; int a = r*LW+c;
          stg[j] = fmaxf(fmaxf(l1[a-1], l1[a]), l1[a+1]);
        }
      }
      __syncthreads();
      #pragma unroll
      for (int j = 0; j < NJ; ++j) {
        int i = tid + 256*j;
        if (i < n) { int r = r0+i/w, c = c0+i%w; l1[r*LW+c] = stg[j]; }
      }
    }
    __syncthreads();
    #pragma unroll
    for (int k = 0; k < 16; ++k) {   // o = col-max; delta; skel += relu(delta - s*delta)
      int i = tid + 256*k;
      int r = HALO + (i>>7), c = HALO + (i&127);
      int a = r*LW + c;
      float o = fmaxf(fmaxf(l1[a-LW], l1[a]), l1[a+LW]);
      float e = l0[a];
      float d = fmaxf(e - o, 0.0f);
      float s = sk[k];
      sk[k] = s + fmaxf(d - s*d, 0.0f);
    }
    __syncthreads();
  }

  // ---- write back skel (+ eroded img for next launch)
  float* So = S + (size_t)img*HW;
  float* Yo = Y + (size_t)img*HW;
  #pragma unroll
  for (int k = 0; k < 16; ++k) {
    int i = tid + 256*k;
    int r = i>>7, c = i&127;
    int go = (gy0+HALO+r)*W + (gx0+HALO+c);
    So[go] = sk[k];
    if (writeY) Yo[go] = l0[(HALO+r)*LW + (HALO+c)];
  }
}

// -------- horizontal 51-tap blur (zero padding), 4 outputs/thread --------
__global__ __launch_bounds__(256)
void blur_h_kernel(const float* __restrict__ Sin, float* __restrict__ D)
{
  __shared__ __align__(16) float row[1080];   // [-25, 1024+25) padded
  const int img = blockIdx.y;
  const int y = blockIdx.x;
  const int tid = threadIdx.x;
  const float* src = Sin + (size_t)img*HW + (size_t)y*W;
  for (int i = tid; i < 1080; i += 256) {
    int x = i - BORDER;
    row[i] = (x >= 0 && x < W) ? src[x] : 0.0f;
  }
  __syncthreads();
  const int x0 = tid * 4;
  float a0=0.f, a1=0.f, a2=0.f, a3=0.f;
  const float4* rp = (const float4*)row;
#define ACCUM(val, idx)                                                     \
  { if ((idx)   >= 0 && (idx)   <= 50) a0 += (val) * GW[(idx)];             \
    if ((idx)-1 >= 0 && (idx)-1 <= 50) a1 += (val) * GW[(idx)-1];           \
    if ((idx)-2 >= 0 && (idx)-2 <= 50) a2 += (val) * GW[(idx)-2];           \
    if ((idx)-3 >= 0 && (idx)-3 <= 50) a3 += (val) * GW[(idx)-3]; }
  #pragma unroll
  for (int t4 = 0; t4 < 14; ++t4) {
    float4 v = rp[tid + t4];
    const int base = 4*t4;
    ACCUM(v.x, base+0) ACCUM(v.y, base+1) ACCUM(v.z, base+2) ACCUM(v.w, base+3)
  }
#undef ACCUM
  float4 outv; outv.x=a0; outv.y=a1; outv.z=a2; outv.w=a3;
  *(float4*)(D + (size_t)img*HW + (size_t)y*W + x0) = outv;
}

// -------- vertical 51-tap blur + clip + soft-dice partial sums (gt,pr pair) --------
#define VTW 64
#define VTH 64
#define VLH (VTH + 2*BORDER)   // 114
__global__ __launch_bounds__(256)
void blur_v_dice_kernel(const float* __restrict__ D, double* __restrict__ sums)
{
  __shared__ float gts[VLH*VTW];
  __shared__ float prs[VLH*VTW];
  __shared__ double rbuf[12];
  const int b = blockIdx.z;
  const int gy0 = blockIdx.y * VTH;
  const int gx0 = blockIdx.x * VTW;
  const int tid = threadIdx.x;
  const float* gsrc = D + (size_t)b*HW;
  const float* psrc = D + (size_t)(b+NB)*HW;
  for (int i = tid; i < VLH*VTW; i += 256) {
    int r = i >> 6, c = i & 63;
    int gy = gy0 - BORDER + r;
    float gv = 0.f, pv = 0.f;
    if (gy >= 0 && gy < H) { int a = gy*W + gx0 + c; gv = gsrc[a]; pv = psrc[a]; }
    gts[i] = gv; prs[i] = pv;
  }
  __syncthreads();
  const int c  = tid & 63;
  const int r0 = (tid >> 6) * 16;   // 16 consecutive output rows per thread
  float ag[16], ap[16];
  #pragma unroll
  for (int j = 0; j < 16; ++j) { ag[j] = 0.f; ap[j] = 0.f; }
  #pragma unroll
  for (int t = 0; t < 16 + KLEN - 1; ++t) {   // sliding reuse: 66 loads -> 16*51 FMAs
    float vg = gts[(r0 + t)*VTW + c];
    float vp = prs[(r0 + t)*VTW + c];
    #pragma unroll
    for (int j = 0; j < 16; ++j) {
      int k = t - j;
      if (k >= 0 && k < KLEN) { ag[j] += vg * GW[k]; ap[j] += vp * GW[k]; }
    }
  }
  double sgp = 0.0, sgg = 0.0, spp = 0.0;
  #pragma unroll
  for (int j = 0; j < 16; ++j) {
    float a = fminf(fmaxf(ag[j], 0.f), 1.f);
    float p = fminf(fmaxf(ap[j], 0.f), 1.f);
    sgp += (double)(a*p); sgg += (double)(a*a); spp += (double)(p*p);
  }
  #pragma unroll
  for (int off = 32; off > 0; off >>= 1) {
    sgp += __shfl_down(sgp, off);
    sgg += __shfl_down(sgg, off);
    spp += __shfl_down(spp, off);
  }
  int lane = tid & 63, wv = tid >> 6;
  if (lane == 0) { rbuf[wv] = sgp; rbuf[4+wv] = sgg; rbuf[8+wv] = spp; }
  __syncthreads();
  if (tid == 0) {
    double a  = rbuf[0]+rbuf[1]+rbuf[2]+rbuf[3];
    double g2 = rbuf[4]+rbuf[5]+rbuf[6]+rbuf[7];
    double p2 = rbuf[8]+rbuf[9]+rbuf[10]+rbuf[11];
    atomicAdd(&sums[b],        a);
    atomicAdd(&sums[NB+b],     g2);
    atomicAdd(&sums[2*NB+b],   p2);
  }
}

__global__ void zero_sums_kernel(double* sums) {
  int t = threadIdx.x;
  if (t < 3*NB) sums[t] = 0.0;
}

__global__ void final_kernel(const double* __restrict__ sums, float* __restrict__ out) {
  if (threadIdx.x == 0) {
    double acc = 0.0;
    for (int b = 0; b < NB; ++b) {
      double num = 2.0*sums[b] + 1e-6;
      double den = sums[NB+b] + sums[2*NB+b] + 1e-6;
      acc += 1.0 - num/den;
    }
    out[0] = (float)(acc / (double)NB);
  }
}

extern "C" void kernel_launch(void* const* d_in, const int* in_sizes, int n_in,
                              void* d_out, int out_size, void* d_ws, size_t ws_size,
                              hipStream_t stream)
{
  (void)in_sizes; (void)n_in; (void)out_size; (void)ws_size;
  const float* pred = (const float*)d_in[0];   // (8,2,1024,1024) f32
  const float* targ = (const float*)d_in[1];   // (8,1024,1024) f32
  float* out = (float*)d_out;

  float* A    = (float*)d_ws;                        // 16*HW floats
  float* Bb   = A  + (size_t)NIMG*HW;                // 16*HW floats
  float* S    = Bb + (size_t)NIMG*HW;                // 16*HW floats (skel)
  double* sums = (double*)(S + (size_t)NIMG*HW);     // 24 doubles

  dim3 pg(W/PTW, H/PTH, NIMG);   // (8,32,16)
  hipLaunchKernelGGL(zero_sums_kernel, dim3(1), dim3(64), 0, stream, sums);
  // init skel + iters 1-2 (reads pred/target directly)
  hipLaunchKernelGGL((skel_kernel<2,true>),  pg, dim3(256), 0, stream,
                     (const float*)nullptr, pred, targ, A, S, 1);
  // iters 3-4 .. 9-10 (last launch skips img write)
  hipLaunchKernelGGL((skel_kernel<2,false>), pg, dim3(256), 0, stream,
                     A,  (const float*)nullptr, (const float*)nullptr, Bb, S, 1);
  hipLaunchKernelGGL((skel_kernel<2,false>), pg, dim3(256), 0, stream,
                     Bb, (const float*)nullptr, (const float*)nullptr, A,  S, 1);
  hipLaunchKernelGGL((skel_kernel<2,false>), pg, dim3(256), 0, stream,
                     A,  (const float*)nullptr, (const float*)nullptr, Bb, S, 1);
  hipLaunchKernelGGL((skel_kernel<2,false>), pg, dim3(256), 0, stream,
                     Bb, (const float*)nullptr, (const float*)nullptr, A,  S, 0);
  // Gaussian border: horizontal then vertical(+dice partial sums)
  hipLaunchKernelGGL(blur_h_kernel, dim3(H, NIMG), dim3(256), 0, stream, S, A);
  hipLaunchKernelGGL(blur_v_dice_kernel, dim3(W/VTW, H/VTH, NB), dim3(256), 0, stream, A, sums);
  hipLaunchKernelGGL(final_kernel, dim3(1), dim3(64), 0, stream, sums, out);
}

// Round 2
// 493.399 us; speedup vs baseline: 2.0881x; 2.0881x over previous
//
#include <hip/hip_runtime.h>

// ---------------- problem constants ----------------
#define H 1024
#define W 1024
#define HW (H*W)
#define NB 8            // batch
#define NIMG 16         // gt batch (0..7) + pred-fg batch (8..15)
#define BORDER 25
#define KLEN 51

// Unnormalized Gaussian weights g[k] = exp(-(k-25)^2/200), k=0..50 (sigma=10).
__device__ __constant__ float GW[KLEN] = {
  0.04393693f, 0.05613476f, 0.07100535f, 0.08892162f, 0.11025053f,
  0.13533528f, 0.16447446f, 0.19789869f, 0.23574608f, 0.27803730f,
  0.32465247f, 0.37531110f, 0.42955736f, 0.48675226f, 0.54607442f,
  0.60653066f, 0.66697681f, 0.72614904f, 0.78270454f, 0.83527021f,
  0.88249690f, 0.92311635f, 0.95599748f, 0.98019867f, 0.99501248f,
  1.00000000f,
  0.99501248f, 0.98019867f, 0.95599748f, 0.92311635f, 0.88249690f,
  0.83527021f, 0.78270454f, 0.72614904f, 0.66697681f, 0.60653066f,
  0.54607442f, 0.48675226f, 0.42955736f, 0.37531110f, 0.32465247f,
  0.27803730f, 0.23574608f, 0.19789869f, 0.16447446f, 0.13533528f,
  0.11025053f, 0.08892162f, 0.07100535f, 0.05613476f, 0.04393693f
};

__device__ inline float m3n(float a,float b,float c){return fminf(fminf(a,b),c);}
__device__ inline float m3x(float a,float b,float c){return fmaxf(fmaxf(a,b),c);}

// Fused skeletonize: per "unit" k computes I_{k+1}=erode(I_k), D_k=dilate(mask(I_{k+1})),
// delta_k=relu(I_k - D_k), skel update. (erode inside open == next iteration's erode)
// All passes uniform over the full LDS buffer in float4; validity erodes <=1/pass from
// buffer edges, halo has slack (checked: worst chain uses 4 of 6/8 halo).
template<int NIT, bool INIT>
__global__ __launch_bounds__(256)
void skel_kernel(const float* __restrict__ X, const float* __restrict__ pred,
                 const float* __restrict__ targ, float* __restrict__ Y,
                 float* __restrict__ S, int writeY)
{
  constexpr int HALOY = 3*NIT;
  constexpr int HXL   = (3*NIT + 3) & ~3;   // x halo rounded up for f4 alignment
  constexpr int LW    = HXL + 64 + HXL;
  constexpr int LW4   = LW/4;
  constexpr int LH    = 64 + 2*HALOY;
  constexpr int NF4   = LW4*LH;
  constexpr int J     = (NF4 + 255)/256;
  constexpr int CR0   = HALOY;              // center start row
  constexpr int CC0   = HXL/4;              // center start f4-col
  constexpr float PINF = __builtin_huge_valf();

  __shared__ float4 Abuf[NF4];
  __shared__ float4 Bbuf[NF4];

  const int img = blockIdx.z;
  const int bx = blockIdx.x, by = blockIdx.y;
  const int gx0 = bx*64 - HXL;              // f4-aligned global x of buffer col 0
  const int gy0 = by*64 - HALOY;
  const int tid = threadIdx.x;
  const bool edge = (gx0 < 0) | (gx0 + LW > W) | (gy0 < 0) | (gy0 + LH > H);

  // ---- load full buffer into A (OOB = +inf, the min identity) ----
  if constexpr (INIT) {
    const int b = img - NB;
    const float4* T4 = reinterpret_cast<const float4*>(targ + (size_t)img*HW);
    const float4* P0 = reinterpret_cast<const float4*>(pred + (size_t)(2*b  )*HW);
    const float4* P1 = reinterpret_cast<const float4*>(pred + (size_t)(2*b+1)*HW);
    #pragma unroll
    for (int j=0;j<J;++j){ int i=tid+256*j; if (i<NF4){
      int r=i/LW4, c=i-r*LW4;
      int gy=gy0+r, gxb=gx0+4*c;
      float4 v = make_float4(PINF,PINF,PINF,PINF);
      if ((unsigned)gy < H && (unsigned)gxb < W) {
        int off = gy*(W/4) + (gxb>>2);
        if (img < NB) v = T4[off];
        else {
          float4 p0 = P0[off], p1 = P1[off];
          v.x = 1.0f/(1.0f + expf(p0.x - p1.x));
          v.y = 1.0f/(1.0f + expf(p0.y - p1.y));
          v.z = 1.0f/(1.0f + expf(p0.z - p1.z));
          v.w = 1.0f/(1.0f + expf(p0.w - p1.w));
        }
      }
      Abuf[i]=v; }}
  } else {
    const float4* Xi = reinterpret_cast<const float4*>(X + (size_t)img*HW);
    #pragma unroll
    for (int j=0;j<J;++j){ int i=tid+256*j; if (i<NF4){
      int r=i/LW4, c=i-r*LW4;
      int gy=gy0+r, gxb=gx0+4*c;
      float4 v = make_float4(PINF,PINF,PINF,PINF);
      if ((unsigned)gy < H && (unsigned)gxb < W) v = Xi[gy*(W/4) + (gxb>>2)];
      Abuf[i]=v; }}
  }

  float4 sk[4], Icen[4];
  if constexpr (!INIT) {
    const float4* S4 = reinterpret_cast<const float4*>(S + (size_t)img*HW);
    #pragma unroll
    for (int k=0;k<4;++k){ int idx=tid+256*k; int cr=idx>>4, cc=idx&15;
      sk[k] = S4[(by*64+cr)*(W/4) + bx*16 + cc]; }
  }
  __syncthreads();

  #pragma unroll
  for (int u=0; u<NIT; ++u) {
    // capture center of I_k (A) for delta
    #pragma unroll
    for (int k=0;k<4;++k){ int idx=tid+256*k; int cr=idx>>4, cc=idx&15;
      Icen[k] = Abuf[(CR0+cr)*LW4 + CC0+cc]; }

    // pass 1: row-min  A -> B
    #pragma unroll
    for (int j=0;j<J;++j){ int i=tid+256*j; if (i<NF4){
      int r=i/LW4, c=i-r*LW4;
      float4 C=Abuf[i];
      float4 L=Abuf[(c==0)?i:i-1];
      float4 R=Abuf[(c==LW4-1)?i:i+1];
      float4 o; o.x=m3n(L.w,C.x,C.y); o.y=m3n(C.x,C.y,C.z);
                o.z=m3n(C.y,C.z,C.w); o.w=m3n(C.z,C.w,R.x);
      Bbuf[i]=o; }}
    __syncthreads();

    // pass 2: col-min  B -> A   (A becomes I_{k+1})
    #pragma unroll
    for (int j=0;j<J;++j){ int i=tid+256*j; if (i<NF4){
      int r=i/LW4;
      float4 C=Bbuf[i];
      float4 U=Bbuf[(r==0)?i:i-LW4];
      float4 D=Bbuf[(r==LH-1)?i:i+LW4];
      float4 o; o.x=m3n(U.x,C.x,D.x); o.y=m3n(U.y,C.y,D.y);
                o.z=m3n(U.z,C.z,D.z); o.w=m3n(U.w,C.w,D.w);
      Abuf[i]=o; }}
    __syncthreads();

    // pass 3: row-max of mask(I_{k+1})  A -> B  (mask: outside image -> -inf)
    if (edge) {
      #pragma unroll
      for (int j=0;j<J;++j){ int i=tid+256*j; if (i<NF4){
        int r=i/LW4, c=i-r*LW4;
        float4 C=Abuf[i];
        float4 L=Abuf[(c==0)?i:i-1];
        float4 R=Abuf[(c==LW4-1)?i:i+1];
        int gy=gy0+r, gxb=gx0+4*c;
        bool yin = (unsigned)gy < H;
        float Lw = (yin && (unsigned)(gxb-1) < W) ? L.w : -PINF;
        float Cx = (yin && (unsigned)(gxb  ) < W) ? C.x : -PINF;
        float Cy = (yin && (unsigned)(gxb+1) < W) ? C.y : -PINF;
        float Cz = (yin && (unsigned)(gxb+2) < W) ? C.z : -PINF;
        float Cw = (yin && (unsigned)(gxb+3) < W) ? C.w : -PINF;
        float Rx = (yin && (unsigned)(gxb+4) < W) ? R.x : -PINF;
        float4 o; o.x=m3x(Lw,Cx,Cy); o.y=m3x(Cx,Cy,Cz);
                  o.z=m3x(Cy,Cz,Cw); o.w=m3x(Cz,Cw,Rx);
        Bbuf[i]=o; }}
    } else {
      #pragma unroll
      for (int j=0;j<J;++j){ int i=tid+256*j; if (i<NF4){
        int r=i/LW4, c=i-r*LW4;
        float4 C=Abuf[i];
        float4 L=Abuf[(c==0)?i:i-1];
        float4 R=Abuf[(c==LW4-1)?i:i+1];
        float4 o; o.x=m3x(L.w,C.x,C.y); o.y=m3x(C.x,C.y,C.z);
                  o.z=m3x(C.y,C.z,C.w); o.w=m3x(C.z,C.w,R.x);
        Bbuf[i]=o; }}
    }
    __syncthreads();

    // pass 4 (center only): col-max -> o; delta = relu(I_k - o); skel update
    #pragma unroll
    for (int k=0;k<4;++k){
      int idx=tid+256*k; int cr=idx>>4, cc=idx&15;
      int a=(CR0+cr)*LW4 + CC0+cc;
      float4 U=Bbuf[a-LW4], C=Bbuf[a], D=Bbuf[a+LW4];
      float ox=m3x(U.x,C.x,D.x), oy=m3x(U.y,C.y,D.y),
            oz=m3x(U.z,C.z,D.z), ow=m3x(U.w,C.w,D.w);
      float4 Ic=Icen[k];
      float dx=fmaxf(Ic.x-ox,0.f), dy=fmaxf(Ic.y-oy,0.f),
            dz=fmaxf(Ic.z-oz,0.f), dw=fmaxf(Ic.w-ow,0.f);
      if (INIT && u==0) {
        sk[k]=make_float4(dx,dy,dz,dw);
      } else {
        sk[k].x = sk[k].x + fmaxf(dx - sk[k].x*dx, 0.f);
        sk[k].y = sk[k].y + fmaxf(dy - sk[k].y*dy, 0.f);
        sk[k].z = sk[k].z + fmaxf(dz - sk[k].z*dz, 0.f);
        sk[k].w = sk[k].w + fmaxf(dw - sk[k].w*dw, 0.f);
      }
    }
    __syncthreads();
  }

  // ---- write back skel (+ eroded img I_{k+NIT} for next launch) ----
  float4* S4o = reinterpret_cast<float4*>(S + (size_t)img*HW);
  float4* Y4o = reinterpret_cast<float4*>(Y + (size_t)img*HW);
  #pragma unroll
  for (int k=0;k<4;++k){
    int idx=tid+256*k; int cr=idx>>4, cc=idx&15;
    int go=(by*64+cr)*(W/4) + bx*16 + cc;
    S4o[go]=sk[k];
    if (writeY) Y4o[go]=Abuf[(CR0+cr)*LW4 + CC0+cc];
  }
}

// -------- horizontal 51-tap blur (zero padding), 4 outputs/thread --------
__global__ __launch_bounds__(256)
void blur_h_kernel(const float* __restrict__ Sin, float* __restrict__ D)
{
  __shared__ __align__(16) float row[1080];   // [-25, 1024+25) padded
  const int img = blockIdx.y;
  const int y = blockIdx.x;
  const int tid = threadIdx.x;
  const float* src = Sin + (size_t)img*HW + (size_t)y*W;
  for (int i = tid; i < 1080; i += 256) {
    int x = i - BORDER;
    row[i] = (x >= 0 && x < W) ? src[x] : 0.0f;
  }
  __syncthreads();
  const int x0 = tid * 4;
  float a0=0.f, a1=0.f, a2=0.f, a3=0.f;
  const float4* rp = (const float4*)row;
#define ACCUM(val, idx)                                                     \
  { if ((idx)   >= 0 && (idx)   <= 50) a0 += (val) * GW[(idx)];             \
    if ((idx)-1 >= 0 && (idx)-1 <= 50) a1 += (val) * GW[(idx)-1];           \
    if ((idx)-2 >= 0 && (idx)-2 <= 50) a2 += (val) * GW[(idx)-2];           \
    if ((idx)-3 >= 0 && (idx)-3 <= 50) a3 += (val) * GW[(idx)-3]; }
  #pragma unroll
  for (int t4 = 0; t4 < 14; ++t4) {
    float4 v = rp[tid + t4];
    const int base = 4*t4;
    ACCUM(v.x, base+0) ACCUM(v.y, base+1) ACCUM(v.z, base+2) ACCUM(v.w, base+3)
  }
#undef ACCUM
  float4 outv; outv.x=a0; outv.y=a1; outv.z=a2; outv.w=a3;
  *(float4*)(D + (size_t)img*HW + (size_t)y*W + x0) = outv;
}

// -------- vertical 51-tap blur + clip + soft-dice partial sums (gt,pr pair) --------
#define VTW 64
#define VTH 64
#define VLH (VTH + 2*BORDER)   // 114
__global__ __launch_bounds__(256)
void blur_v_dice_kernel(const float* __restrict__ D, double* __restrict__ sums)
{
  __shared__ float gts[VLH*VTW];
  __shared__ float prs[VLH*VTW];
  __shared__ double rbuf[12];
  const int b = blockIdx.z;
  const int gy0 = blockIdx.y * VTH;
  const int gx0 = blockIdx.x * VTW;
  const int tid = threadIdx.x;
  const float* gsrc = D + (size_t)b*HW;
  const float* psrc = D + (size_t)(b+NB)*HW;
  for (int i = tid; i < VLH*VTW; i += 256) {
    int r = i >> 6, c = i & 63;
    int gy = gy0 - BORDER + r;
    float gv = 0.f, pv = 0.f;
    if (gy >= 0 && gy < H) { int a = gy*W + gx0 + c; gv = gsrc[a]; pv = psrc[a]; }
    gts[i] = gv; prs[i] = pv;
  }
  __syncthreads();
  const int c  = tid & 63;
  const int r0 = (tid >> 6) * 16;   // 16 consecutive output rows per thread
  float ag[16], ap[16];
  #pragma unroll
  for (int j = 0; j < 16; ++j) { ag[j] = 0.f; ap[j] = 0.f; }
  #pragma unroll
  for (int t = 0; t < 16 + KLEN - 1; ++t) {   // sliding reuse: 66 loads -> 16*51 FMAs
    float vg = gts[(r0 + t)*VTW + c];
    float vp = prs[(r0 + t)*VTW + c];
    #pragma unroll
    for (int j = 0; j < 16; ++j) {
      int k = t - j;
      if (k >= 0 && k < KLEN) { ag[j] += vg * GW[k]; ap[j] += vp * GW[k]; }
    }
  }
  double sgp = 0.0, sgg = 0.0, spp = 0.0;
  #pragma unroll
  for (int j = 0; j < 16; ++j) {
    float a = fminf(fmaxf(ag[j], 0.f), 1.f);
    float p = fminf(fmaxf(ap[j], 0.f), 1.f);
    sgp += (double)(a*p); sgg += (double)(a*a); spp += (double)(p*p);
  }
  #pragma unroll
  for (int off = 32; off > 0; off >>= 1) {
    sgp += __shfl_down(sgp, off);
    sgg += __shfl_down(sgg, off);
    spp += __shfl_down(spp, off);
  }
  int lane = tid & 63, wv = tid >> 6;
  if (lane == 0) { rbuf[wv] = sgp; rbuf[4+wv] = sgg; rbuf[8+wv] = spp; }
  __syncthreads();
  if (tid == 0) {
    double a  = rbuf[0]+rbuf[1]+rbuf[2]+rbuf[3];
    double g2 = rbuf[4]+rbuf[5]+rbuf[6]+rbuf[7];
    double p2 = rbuf[8]+rbuf[9]+rbuf[10]+rbuf[11];
    atomicAdd(&sums[b],        a);
    atomicAdd(&sums[NB+b],     g2);
    atomicAdd(&sums[2*NB+b],   p2);
  }
}

__global__ void zero_sums_kernel(double* sums) {
  int t = threadIdx.x;
  if (t < 3*NB) sums[t] = 0.0;
}

__global__ void final_kernel(const double* __restrict__ sums, float* __restrict__ out) {
  if (threadIdx.x == 0) {
    double acc = 0.0;
    for (int b = 0; b < NB; ++b) {
      double num = 2.0*sums[b] + 1e-6;
      double den = sums[NB+b] + sums[2*NB+b] + 1e-6;
      acc += 1.0 - num/den;
    }
    out[0] = (float)(acc / (double)NB);
  }
}

extern "C" void kernel_launch(void* const* d_in, const int* in_sizes, int n_in,
                              void* d_out, int out_size, void* d_ws, size_t ws_size,
                              hipStream_t stream)
{
  (void)in_sizes; (void)n_in; (void)out_size; (void)ws_size;
  const float* pred = (const float*)d_in[0];   // (8,2,1024,1024) f32
  const float* targ = (const float*)d_in[1];   // (8,1024,1024) f32
  float* out = (float*)d_out;

  float* A    = (float*)d_ws;                        // 16*HW floats
  float* Bb   = A  + (size_t)NIMG*HW;                // 16*HW floats
  float* S    = Bb + (size_t)NIMG*HW;                // 16*HW floats (skel)
  double* sums = (double*)(S + (size_t)NIMG*HW);     // 24 doubles

  dim3 pg(16, 16, NIMG);
  hipLaunchKernelGGL(zero_sums_kernel, dim3(1), dim3(64), 0, stream, sums);
  // units 0,1 (init: skel=delta0) -> outputs I_2
  hipLaunchKernelGGL((skel_kernel<2,true>),  pg, dim3(256), 0, stream,
                     (const float*)nullptr, pred, targ, A, S, 1);
  // units 2,3 -> I_4 ; 4,5 -> I_6 ; 6,7 -> I_8 ; 8,9 -> I_10
  hipLaunchKernelGGL((skel_kernel<2,false>), pg, dim3(256), 0, stream,
                     A,  (const float*)nullptr, (const float*)nullptr, Bb, S, 1);
  hipLaunchKernelGGL((skel_kernel<2,false>), pg, dim3(256), 0, stream,
                     Bb, (const float*)nullptr, (const float*)nullptr, A,  S, 1);
  hipLaunchKernelGGL((skel_kernel<2,false>), pg, dim3(256), 0, stream,
                     A,  (const float*)nullptr, (const float*)nullptr, Bb, S, 1);
  hipLaunchKernelGGL((skel_kernel<2,false>), pg, dim3(256), 0, stream,
                     Bb, (const float*)nullptr, (const float*)nullptr, A,  S, 1);
  // unit 10 (no img output)
  hipLaunchKernelGGL((skel_kernel<1,false>), pg, dim3(256), 0, stream,
                     A,  (const float*)nullptr, (const float*)nullptr, Bb, S, 0);
  // Gaussian border: horizontal then vertical(+dice partial sums)
  hipLaunchKernelGGL(blur_h_kernel, dim3(H, NIMG), dim3(256), 0, stream, S, A);
  hipLaunchKernelGGL(blur_v_dice_kernel, dim3(W/VTW, H/VTH, NB), dim3(256), 0, stream, A, sums);
  hipLaunchKernelGGL(final_kernel, dim3(1), dim3(64), 0, stream, sums, out);
}

// Round 3
// 482.867 us; speedup vs baseline: 2.1337x; 1.0218x over previous
//
#include <hip/hip_runtime.h>

// ---------------- problem constants ----------------
#define H 1024
#define W 1024
#define HW (H*W)
#define NB 8            // batch
#define NIMG 16         // gt batch (0..7) + pred-fg batch (8..15)
#define BORDER 25
#define KLEN 51

// Unnormalized Gaussian weights g[k] = exp(-(k-25)^2/200), k=0..50 (sigma=10).
__device__ __constant__ float GW[KLEN] = {
  0.04393693f, 0.05613476f, 0.07100535f, 0.08892162f, 0.11025053f,
  0.13533528f, 0.16447446f, 0.19789869f, 0.23574608f, 0.27803730f,
  0.32465247f, 0.37531110f, 0.42955736f, 0.48675226f, 0.54607442f,
  0.60653066f, 0.66697681f, 0.72614904f, 0.78270454f, 0.83527021f,
  0.88249690f, 0.92311635f, 0.95599748f, 0.98019867f, 0.99501248f,
  1.00000000f,
  0.99501248f, 0.98019867f, 0.95599748f, 0.92311635f, 0.88249690f,
  0.83527021f, 0.78270454f, 0.72614904f, 0.66697681f, 0.60653066f,
  0.54607442f, 0.48675226f, 0.42955736f, 0.37531110f, 0.32465247f,
  0.27803730f, 0.23574608f, 0.19789869f, 0.16447446f, 0.13533528f,
  0.11025053f, 0.08892162f, 0.07100535f, 0.05613476f, 0.04393693f
};

__device__ inline float m3n(float a,float b,float c){return fminf(fminf(a,b),c);}
__device__ inline float m3x(float a,float b,float c){return fmaxf(fmaxf(a,b),c);}

// Fused skeletonize, column-strip form.
// Unit k: I_{k+1}=erode(I_k) (in-place, in-register V-sliding); delta_k =
// relu(I_k - dilate(mask(I_{k+1}))); s += relu(d - s*d) (s=d at very first unit).
// Freshness: processed row margin PY_u grows +1/unit; chain F_u=max(PY_u,F_{u-1}+1)
// stays below what dilate/center need (K1: F=17<21-1+..; K2: F=5<11). X margin fixed
// at f4-col [1,LW4-1): F^x <= NIT+3 <= HXL-4 for both kernels.
template<int NIT, bool INIT, bool WRITEY>
__global__ __launch_bounds__(512, 4)
void skel_kernel(const float* __restrict__ X, const float* __restrict__ pred,
                 const float* __restrict__ targ, float* __restrict__ Y,
                 float* __restrict__ S)
{
  constexpr int HALOY = 3*NIT;
  constexpr int HXL   = (3*NIT + 3) & ~3;       // x halo (scalars), f4-aligned
  constexpr int LW4   = (2*HXL + 64)/4;         // buffer width in f4
  constexpr int ST    = LW4 + 1;                // LDS row stride (odd -> bank decorrelate)
  constexpr int LH    = 64 + 2*HALOY;           // buffer height
  constexpr int NBAND = 512/LW4;
  constexpr int ROWS  = (LH + NBAND - 1)/NBAND; // rows per band
  constexpr int CR0   = HALOY;                  // center rows [CR0, CR0+64)
  constexpr int CC4   = HXL/4;                  // center f4-cols [CC4, CC4+16)
  constexpr int PY0   = (NIT >= 5) ? (HALOY-10) : 2;
  constexpr float PINF = __builtin_huge_valf();

  __shared__ float4 Abuf[ST*LH];
  float* Af = (float*)Abuf;

  const int img = blockIdx.z;
  const int bx = blockIdx.x, by = blockIdx.y;
  const int gx0 = bx*64 - HXL, gy0 = by*64 - HALOY;
  const int tid = threadIdx.x;
  const int band = tid / LW4;
  const int c = tid - band*LW4;
  const bool act = (band < NBAND);
  const int r0 = act ? band*ROWS : LH;
  const int r1 = act ? min(r0+ROWS, LH) : LH;
  const bool edge = (bx==0)||(by==0)||(bx==15)||(by==15);
  const bool ecol = act && (c >= 1) && (c < LW4-1);
  const bool ccen = act && (c >= CC4) && (c < CC4+16);
  const int dlo = max(r0, CR0);
  const int dhi = min(r1, CR0+64);

  // ---- load strip (OOB = +inf, the min identity) ----
  if (act) {
    #pragma unroll
    for (int k=0;k<ROWS;++k) {
      int r = r0+k;
      if (r < r1) {
        int gy = gy0+r, gxb = gx0+4*c;
        float4 v = make_float4(PINF,PINF,PINF,PINF);
        if ((unsigned)gy < H && (unsigned)gxb < W) {
          int off = gy*(W/4) + (gxb>>2);
          if constexpr (INIT) {
            if (img < NB) v = ((const float4*)targ)[(size_t)img*(HW/4)+off];
            else {
              int b = img-NB;
              float4 p0 = ((const float4*)pred)[(size_t)(2*b  )*(HW/4)+off];
              float4 p1 = ((const float4*)pred)[(size_t)(2*b+1)*(HW/4)+off];
              v.x = 1.0f/(1.0f + expf(p0.x - p1.x));
              v.y = 1.0f/(1.0f + expf(p0.y - p1.y));
              v.z = 1.0f/(1.0f + expf(p0.z - p1.z));
              v.w = 1.0f/(1.0f + expf(p0.w - p1.w));
            }
          } else {
            v = ((const float4*)X)[(size_t)img*(HW/4)+off];
          }
        }
        Abuf[r*ST+c] = v;
      }
    }
  }

  float4 sreg[ROWS], icen[ROWS], oreg[ROWS];
  if constexpr (!INIT) {
    if (ccen) {
      #pragma unroll
      for (int k=0;k<ROWS;++k) {
        int rr = r0+k;
        if (rr>=dlo && rr<dhi)
          sreg[k] = ((const float4*)S)[(size_t)img*(HW/4)
                      + (size_t)(by*64 + rr - CR0)*(W/4) + bx*16 + (c-CC4)];
      }
    }
  }
  __syncthreads();

  for (int u=0; u<NIT; ++u) {
    const int PY = PY0 + u;
    const int elo = max(r0, PY), ehi = min(r1, LH-PY);

    // ---- erode: H-min (1 f4 + 2 scalar reads) + in-reg V-slide; capture I_k center ----
    {
      float4 h0=make_float4(0,0,0,0), h1=h0, h2=h0;
      #pragma unroll
      for (int k=0;k<ROWS+2;++k) {
        const int r = r0 + k - 1;
        h0 = h1; h1 = h2;
        if (ecol && r >= elo-1 && r <= ehi) {
          const int a = r*ST + c;
          float4 C = Abuf[a];
          float Lw = Af[4*a - 1];
          float Rx = Af[4*a + 4];
          h2.x = m3n(Lw , C.x, C.y);
          h2.y = m3n(C.x, C.y, C.z);
          h2.z = m3n(C.y, C.z, C.w);
          h2.w = m3n(C.z, C.w, Rx );
          if (ccen && r >= dlo && r < dhi) icen[k-1] = C;
        }
        if (k >= 2) {
          const int rr = r0 + k - 2;
          if (ecol && rr >= elo && rr < ehi) {
            oreg[k-2].x = m3n(h0.x, h1.x, h2.x);
            oreg[k-2].y = m3n(h0.y, h1.y, h2.y);
            oreg[k-2].z = m3n(h0.z, h1.z, h2.z);
            oreg[k-2].w = m3n(h0.w, h1.w, h2.w);
          }
        }
      }
    }
    __syncthreads();
    #pragma unroll
    for (int k=0;k<ROWS;++k) {
      int rr = r0+k;
      if (ecol && rr >= elo && rr < ehi) Abuf[rr*ST+c] = oreg[k];
    }
    __syncthreads();

    // ---- dilate (masked, center only) + delta + skel update; no LDS writes ----
    {
      float4 h0=make_float4(0,0,0,0), h1=h0, h2=h0;
      #pragma unroll
      for (int k=0;k<ROWS+2;++k) {
        const int r = r0 + k - 1;
        h0 = h1; h1 = h2;
        if (ccen && r >= dlo-1 && r <= dhi) {
          const int a = r*ST + c;
          float4 C = Abuf[a];
          float Lw = Af[4*a - 1];
          float Rx = Af[4*a + 4];
          if (edge) {
            if ((unsigned)(gy0 + r) >= H) {
              C = make_float4(-PINF,-PINF,-PINF,-PINF); Lw = -PINF; Rx = -PINF;
            } else {
              int gxb = gx0 + 4*c;
              if (gxb - 1 < 0)  Lw = -PINF;
              if (gxb + 4 >= W) Rx = -PINF;
            }
          }
          h2.x = m3x(Lw , C.x, C.y);
          h2.y = m3x(C.x, C.y, C.z);
          h2.z = m3x(C.y, C.z, C.w);
          h2.w = m3x(C.z, C.w, Rx );
        }
        if (k >= 2) {
          const int rr = r0 + k - 2;
          if (ccen && rr >= dlo && rr < dhi) {
            float ox = m3x(h0.x, h1.x, h2.x);
            float oy = m3x(h0.y, h1.y, h2.y);
            float oz = m3x(h0.z, h1.z, h2.z);
            float ow = m3x(h0.w, h1.w, h2.w);
            float4 Ic = icen[k-2];
            float dx = fmaxf(Ic.x - ox, 0.f);
            float dy = fmaxf(Ic.y - oy, 0.f);
            float dz = fmaxf(Ic.z - oz, 0.f);
            float dw = fmaxf(Ic.w - ow, 0.f);
            if (INIT && u == 0) {
              sreg[k-2] = make_float4(dx,dy,dz,dw);
            } else {
              float4 s = sreg[k-2];
              s.x += fmaxf(dx - s.x*dx, 0.f);
              s.y += fmaxf(dy - s.y*dy, 0.f);
              s.z += fmaxf(dz - s.z*dz, 0.f);
              s.w += fmaxf(dw - s.w*dw, 0.f);
              sreg[k-2] = s;
            }
          }
        }
      }
    }
    // no sync needed: next phase begins with reads; writes wait on its barrier
  }

  // ---- store skel (+ eroded img carry) ----
  if (ccen) {
    #pragma unroll
    for (int k=0;k<ROWS;++k) {
      int rr = r0+k;
      if (rr >= dlo && rr < dhi) {
        size_t go = (size_t)img*(HW/4)
                  + (size_t)(by*64 + rr - CR0)*(W/4) + bx*16 + (c-CC4);
        ((float4*)S)[go] = sreg[k];
        if constexpr (WRITEY) ((float4*)Y)[go] = Abuf[rr*ST+c];
      }
    }
  }
}

// -------- horizontal 51-tap blur (zero padding), 4 outputs/thread --------
__global__ __launch_bounds__(256)
void blur_h_kernel(const float* __restrict__ Sin, float* __restrict__ D)
{
  __shared__ __align__(16) float row[1080];   // [-25, 1024+25) padded
  const int img = blockIdx.y;
  const int y = blockIdx.x;
  const int tid = threadIdx.x;
  const float* src = Sin + (size_t)img*HW + (size_t)y*W;
  for (int i = tid; i < 1080; i += 256) {
    int x = i - BORDER;
    row[i] = (x >= 0 && x < W) ? src[x] : 0.0f;
  }
  __syncthreads();
  const int x0 = tid * 4;
  float a0=0.f, a1=0.f, a2=0.f, a3=0.f;
  const float4* rp = (const float4*)row;
#define ACCUM(val, idx)                                                     \
  { if ((idx)   >= 0 && (idx)   <= 50) a0 += (val) * GW[(idx)];             \
    if ((idx)-1 >= 0 && (idx)-1 <= 50) a1 += (val) * GW[(idx)-1];           \
    if ((idx)-2 >= 0 && (idx)-2 <= 50) a2 += (val) * GW[(idx)-2];           \
    if ((idx)-3 >= 0 && (idx)-3 <= 50) a3 += (val) * GW[(idx)-3]; }
  #pragma unroll
  for (int t4 = 0; t4 < 14; ++t4) {
    float4 v = rp[tid + t4];
    const int base = 4*t4;
    ACCUM(v.x, base+0) ACCUM(v.y, base+1) ACCUM(v.z, base+2) ACCUM(v.w, base+3)
  }
#undef ACCUM
  float4 outv; outv.x=a0; outv.y=a1; outv.z=a2; outv.w=a3;
  *(float4*)(D + (size_t)img*HW + (size_t)y*W + x0) = outv;
}

// -------- vertical 51-tap blur + clip + soft-dice partial sums (gt,pr pair) --------
#define VTW 64
#define VTH 64
#define VLH (VTH + 2*BORDER)   // 114
__global__ __launch_bounds__(256)
void blur_v_dice_kernel(const float* __restrict__ D, double* __restrict__ sums)
{
  __shared__ float gts[VLH*VTW];
  __shared__ float prs[VLH*VTW];
  __shared__ double rbuf[12];
  const int b = blockIdx.z;
  const int gy0 = blockIdx.y * VTH;
  const int gx0 = blockIdx.x * VTW;
  const int tid = threadIdx.x;
  const float* gsrc = D + (size_t)b*HW;
  const float* psrc = D + (size_t)(b+NB)*HW;
  for (int i = tid; i < VLH*VTW; i += 256) {
    int r = i >> 6, c = i & 63;
    int gy = gy0 - BORDER + r;
    float gv = 0.f, pv = 0.f;
    if (gy >= 0 && gy < H) { int a = gy*W + gx0 + c; gv = gsrc[a]; pv = psrc[a]; }
    gts[i] = gv; prs[i] = pv;
  }
  __syncthreads();
  const int c  = tid & 63;
  const int r0 = (tid >> 6) * 16;   // 16 consecutive output rows per thread
  float ag[16], ap[16];
  #pragma unroll
  for (int j = 0; j < 16; ++j) { ag[j] = 0.f; ap[j] = 0.f; }
  #pragma unroll
  for (int t = 0; t < 16 + KLEN - 1; ++t) {   // sliding reuse: 66 loads -> 16*51 FMAs
    float vg = gts[(r0 + t)*VTW + c];
    float vp = prs[(r0 + t)*VTW + c];
    #pragma unroll
    for (int j = 0; j < 16; ++j) {
      int k = t - j;
      if (k >= 0 && k < KLEN) { ag[j] += vg * GW[k]; ap[j] += vp * GW[k]; }
    }
  }
  double sgp = 0.0, sgg = 0.0, spp = 0.0;
  #pragma unroll
  for (int j = 0; j < 16; ++j) {
    float a = fminf(fmaxf(ag[j], 0.f), 1.f);
    float p = fminf(fmaxf(ap[j], 0.f), 1.f);
    sgp += (double)(a*p); sgg += (double)(a*a); spp += (double)(p*p);
  }
  #pragma unroll
  for (int off = 32; off > 0; off >>= 1) {
    sgp += __shfl_down(sgp, off);
    sgg += __shfl_down(sgg, off);
    spp += __shfl_down(spp, off);
  }
  int lane = tid & 63, wv = tid >> 6;
  if (lane == 0) { rbuf[wv] = sgp; rbuf[4+wv] = sgg; rbuf[8+wv] = spp; }
  __syncthreads();
  if (tid == 0) {
    double a  = rbuf[0]+rbuf[1]+rbuf[2]+rbuf[3];
    double g2 = rbuf[4]+rbuf[5]+rbuf[6]+rbuf[7];
    double p2 = rbuf[8]+rbuf[9]+rbuf[10]+rbuf[11];
    atomicAdd(&sums[b],        a);
    atomicAdd(&sums[NB+b],     g2);
    atomicAdd(&sums[2*NB+b],   p2);
  }
}

__global__ void zero_sums_kernel(double* sums) {
  int t = threadIdx.x;
  if (t < 3*NB) sums[t] = 0.0;
}

__global__ void final_kernel(const double* __restrict__ sums, float* __restrict__ out) {
  if (threadIdx.x == 0) {
    double acc = 0.0;
    for (int b = 0; b < NB; ++b) {
      double num = 2.0*sums[b] + 1e-6;
      double den = sums[NB+b] + sums[2*NB+b] + 1e-6;
      acc += 1.0 - num/den;
    }
    out[0] = (float)(acc / (double)NB);
  }
}

extern "C" void kernel_launch(void* const* d_in, const int* in_sizes, int n_in,
                              void* d_out, int out_size, void* d_ws, size_t ws_size,
                              hipStream_t stream)
{
  (void)in_sizes; (void)n_in; (void)out_size; (void)ws_size;
  const float* pred = (const float*)d_in[0];   // (8,2,1024,1024) f32
  const float* targ = (const float*)d_in[1];   // (8,1024,1024) f32
  float* out = (float*)d_out;

  float* Ybuf = (float*)d_ws;                        // 16*HW floats (img carry / blur tmp)
  float* Sbuf = Ybuf + (size_t)NIMG*HW;              // 16*HW floats (skel state)
  double* sums = (double*)(Sbuf + (size_t)NIMG*HW);  // 24 doubles

  dim3 pg(16, 16, NIMG);
  hipLaunchKernelGGL(zero_sums_kernel, dim3(1), dim3(64), 0, stream, sums);
  // units 0-6 (init: s=delta0), writes Y=I_7 and S carry
  hipLaunchKernelGGL((skel_kernel<7,true,true>), pg, dim3(512), 0, stream,
                     (const float*)nullptr, pred, targ, Ybuf, Sbuf);
  // units 7-10, final skel into Sbuf
  hipLaunchKernelGGL((skel_kernel<4,false,false>), pg, dim3(512), 0, stream,
                     Ybuf, (const float*)nullptr, (const float*)nullptr,
                     (float*)nullptr, Sbuf);
  // Gaussian border: horizontal then vertical(+dice partial sums)
  hipLaunchKernelGGL(blur_h_kernel, dim3(H, NIMG), dim3(256), 0, stream, Sbuf, Ybuf);
  hipLaunchKernelGGL(blur_v_dice_kernel, dim3(W/VTW, H/VTH, NB), dim3(256), 0, stream, Ybuf, sums);
  hipLaunchKernelGGL(final_kernel, dim3(1), dim3(64), 0, stream, sums, out);
}

// Round 4
// 374.283 us; speedup vs baseline: 2.7527x; 1.2901x over previous
//
#include <hip/hip_runtime.h>

// ---------------- problem constants ----------------
#define H 1024
#define W 1024
#define HW (H*W)
#define NB 8            // batch
#define NIMG 16         // gt batch (0..7) + pred-fg batch (8..15)
#define BORDER 25
#define KLEN 51

// Unnormalized Gaussian weights g[k] = exp(-(k-25)^2/200), k=0..50 (sigma=10).
__device__ __constant__ float GW[KLEN] = {
  0.04393693f, 0.05613476f, 0.07100535f, 0.08892162f, 0.11025053f,
  0.13533528f, 0.16447446f, 0.19789869f, 0.23574608f, 0.27803730f,
  0.32465247f, 0.37531110f, 0.42955736f, 0.48675226f, 0.54607442f,
  0.60653066f, 0.66697681f, 0.72614904f, 0.78270454f, 0.83527021f,
  0.88249690f, 0.92311635f, 0.95599748f, 0.98019867f, 0.99501248f,
  1.00000000f,
  0.99501248f, 0.98019867f, 0.95599748f, 0.92311635f, 0.88249690f,
  0.83527021f, 0.78270454f, 0.72614904f, 0.66697681f, 0.60653066f,
  0.54607442f, 0.48675226f, 0.42955736f, 0.37531110f, 0.32465247f,
  0.27803730f, 0.23574608f, 0.19789869f, 0.16447446f, 0.13533528f,
  0.11025053f, 0.08892162f, 0.07100535f, 0.05613476f, 0.04393693f
};

__device__ inline float m3n(float a,float b,float c){return fminf(fminf(a,b),c);}
__device__ inline float m3x(float a,float b,float c){return fmaxf(fmaxf(a,b),c);}

__device__ inline float4 hmin4(float4 C){
  float Lw = __shfl_up(C.w, 1, 32);     // left neighbor f4's .w (reg-file xlane)
  float Rx = __shfl_down(C.x, 1, 32);   // right neighbor f4's .x
  float4 h;
  h.x=m3n(Lw ,C.x,C.y); h.y=m3n(C.x,C.y,C.z);
  h.z=m3n(C.y,C.z,C.w); h.w=m3n(C.z,C.w,Rx );
  return h;
}
__device__ inline float4 hmax4(float4 C){
  float Lw = __shfl_up(C.w, 1, 32);
  float Rx = __shfl_down(C.x, 1, 32);
  float4 h;
  h.x=m3x(Lw ,C.x,C.y); h.y=m3x(C.x,C.y,C.z);
  h.z=m3x(C.y,C.z,C.w); h.w=m3x(C.z,C.w,Rx );
  return h;
}
__device__ inline float4 vmin3(float4 a,float4 b,float4 c){
  float4 o; o.x=m3n(a.x,b.x,c.x); o.y=m3n(a.y,b.y,c.y);
            o.z=m3n(a.z,b.z,c.z); o.w=m3n(a.w,b.w,c.w); return o;
}
__device__ inline float4 vmax3(float4 a,float4 b,float4 c){
  float4 o; o.x=m3x(a.x,b.x,c.x); o.y=m3x(a.y,b.y,c.y);
            o.z=m3x(a.z,b.z,c.z); o.w=m3x(a.w,b.w,c.w); return o;
}
__device__ inline float4 msk4(float4 e, bool v){
  constexpr float NINF = -__builtin_huge_valf();
  float4 o; o.x=v?e.x:NINF; o.y=v?e.y:NINF; o.z=v?e.z:NINF; o.w=v?e.w:NINF;
  return o;
}

// Register-resident fused skeletonize.
// Buffer: 32 f4 (128 px) x 80 rows; center f4-cols [8,24), rows [8,72).
// 512 threads = 16 groups x 32 lanes; group g owns rows [5g,5g+5) in registers.
// Horizontal 3-taps via __shfl within 32-lane groups; vertical group-boundary
// rows exchanged through a tiny LDS buffer (contiguous b128, conflict-free).
// Unit u: I_{u+1}=erode(I_u); delta=relu(I_u - dilate(mask(I_{u+1})));
// s += relu(d - s*d) (s=d at the very first unit). Exact vs reference:
// +inf padding == valid-only min; mask makes dilate valid-only.
// Freshness: erode invalidates 1 f4-col + 1 row per side per unit; dilate
// needs center+-1 => u+1 <= 7 (halo 8) — NIT<=7 exact.
template<int NIT, bool INIT, bool WRITEY>
__global__ __launch_bounds__(512, 4)
void skel_kernel(const float* __restrict__ X, const float* __restrict__ pred,
                 const float* __restrict__ targ, float* __restrict__ Y,
                 float* __restrict__ S)
{
  constexpr float PINF = __builtin_huge_valf();
  __shared__ float4 Xch[2][32][32];   // [slot][2 rows/group *16][f4-col] = 32 KB

  const int img = blockIdx.z;
  const int bx = blockIdx.x, by = blockIdx.y;
  const int gx0 = bx*64 - 32, gy0 = by*64 - 8;
  const int tid = threadIdx.x;
  const int g = tid >> 5;             // 16 row-groups
  const int j = tid & 31;             // f4-col within buffer row
  const int R0 = 5*g;
  const int gxb = gx0 + 4*j;
  const bool xok = ((unsigned)gxb < (unsigned)W);
  const bool cenj = (j >= 8) && (j < 24);

  float4 I[5], s[5];

  // ---- load 5 rows into registers (OOB = +inf, the min identity) ----
  #pragma unroll
  for (int k=0;k<5;++k) {
    int gy = gy0 + R0 + k;
    float4 v = make_float4(PINF,PINF,PINF,PINF);
    if (((unsigned)gy < (unsigned)H) && xok) {
      size_t off = (size_t)gy*(W/4) + (gxb>>2);
      if constexpr (INIT) {
        if (img < NB) v = ((const float4*)targ)[(size_t)img*(HW/4)+off];
        else {
          int b2 = img - NB;
          float4 p0 = ((const float4*)pred)[(size_t)(2*b2  )*(HW/4)+off];
          float4 p1 = ((const float4*)pred)[(size_t)(2*b2+1)*(HW/4)+off];
          v.x = 1.0f/(1.0f + expf(p0.x - p1.x));
          v.y = 1.0f/(1.0f + expf(p0.y - p1.y));
          v.z = 1.0f/(1.0f + expf(p0.z - p1.z));
          v.w = 1.0f/(1.0f + expf(p0.w - p1.w));
        }
      } else {
        v = ((const float4*)X)[(size_t)img*(HW/4)+off];
      }
    }
    I[k] = v;
  }
  if constexpr (!INIT) {
    if (cenj) {
      #pragma unroll
      for (int k=0;k<5;++k) {
        int rr = R0+k;
        if (rr>=8 && rr<72)
          s[k] = ((const float4*)S)[(size_t)img*(HW/4)
                   + (size_t)(by*64+rr-8)*(W/4) + bx*16 + (j-8)];
      }
    }
  }

  for (int u=0; u<NIT; ++u) {
    // ---- erode: H-min in regs/shuffles, exchange group-boundary rows ----
    float4 h[5];
    #pragma unroll
    for (int k=0;k<5;++k) h[k] = hmin4(I[k]);
    Xch[0][2*g  ][j] = h[0];
    Xch[0][2*g+1][j] = h[4];
    __syncthreads();
    float4 hm = (g>0)  ? Xch[0][2*g-1][j] : h[0];   // row R0-1 (clamp at top)
    float4 hp = (g<15) ? Xch[0][2*g+2][j] : h[4];   // row R0+5 (clamp at bot)
    float4 e[5];
    e[0] = vmin3(hm ,h[0],h[1]);
    e[1] = vmin3(h[0],h[1],h[2]);
    e[2] = vmin3(h[1],h[2],h[3]);
    e[3] = vmin3(h[2],h[3],h[4]);
    e[4] = vmin3(h[3],h[4],hp );

    // ---- dilate of masked I_{u+1} (mask: outside image -> -inf) ----
    float4 x[5];
    #pragma unroll
    for (int k=0;k<5;++k) {
      bool yok = ((unsigned)(gy0+R0+k) < (unsigned)H);
      x[k] = hmax4(msk4(e[k], xok && yok));
    }
    Xch[1][2*g  ][j] = x[0];
    Xch[1][2*g+1][j] = x[4];
    __syncthreads();
    float4 xm = (g>0)  ? Xch[1][2*g-1][j] : x[0];
    float4 xp = (g<15) ? Xch[1][2*g+2][j] : x[4];

    // ---- delta + skel update + commit I_{u+1} ----
    #pragma unroll
    for (int k=0;k<5;++k) {
      float4 dl = vmax3((k==0)?xm:x[k-1], x[k], (k==4)?xp:x[k+1]);
      float4 Ik = I[k];
      float dx = fmaxf(Ik.x-dl.x,0.f), dy = fmaxf(Ik.y-dl.y,0.f);
      float dz = fmaxf(Ik.z-dl.z,0.f), dw = fmaxf(Ik.w-dl.w,0.f);
      if (INIT && u==0) {
        s[k] = make_float4(dx,dy,dz,dw);
      } else {
        s[k].x += fmaxf(dx - s[k].x*dx, 0.f);
        s[k].y += fmaxf(dy - s[k].y*dy, 0.f);
        s[k].z += fmaxf(dz - s[k].z*dz, 0.f);
        s[k].w += fmaxf(dw - s[k].w*dw, 0.f);
      }
      I[k] = e[k];
    }
  }

  // ---- write back skel (+ eroded img carry for next launch) ----
  if (cenj) {
    #pragma unroll
    for (int k=0;k<5;++k) {
      int rr = R0+k;
      if (rr>=8 && rr<72) {
        size_t off = (size_t)img*(HW/4)
                   + (size_t)(by*64+rr-8)*(W/4) + bx*16 + (j-8);
        ((float4*)S)[off] = s[k];
        if constexpr (WRITEY) ((float4*)Y)[off] = I[k];
      }
    }
  }
}

// -------- horizontal 51-tap blur (zero padding), 4 outputs/thread --------
__global__ __launch_bounds__(256)
void blur_h_kernel(const float* __restrict__ Sin, float* __restrict__ D)
{
  __shared__ __align__(16) float row[1080];   // [-25, 1024+25) padded
  const int img = blockIdx.y;
  const int y = blockIdx.x;
  const int tid = threadIdx.x;
  const float* src = Sin + (size_t)img*HW + (size_t)y*W;
  for (int i = tid; i < 1080; i += 256) {
    int x = i - BORDER;
    row[i] = (x >= 0 && x < W) ? src[x] : 0.0f;
  }
  __syncthreads();
  const int x0 = tid * 4;
  float a0=0.f, a1=0.f, a2=0.f, a3=0.f;
  const float4* rp = (const float4*)row;
#define ACCUM(val, idx)                                                     \
  { if ((idx)   >= 0 && (idx)   <= 50) a0 += (val) * GW[(idx)];             \
    if ((idx)-1 >= 0 && (idx)-1 <= 50) a1 += (val) * GW[(idx)-1];           \
    if ((idx)-2 >= 0 && (idx)-2 <= 50) a2 += (val) * GW[(idx)-2];           \
    if ((idx)-3 >= 0 && (idx)-3 <= 50) a3 += (val) * GW[(idx)-3]; }
  #pragma unroll
  for (int t4 = 0; t4 < 14; ++t4) {
    float4 v = rp[tid + t4];
    const int base = 4*t4;
    ACCUM(v.x, base+0) ACCUM(v.y, base+1) ACCUM(v.z, base+2) ACCUM(v.w, base+3)
  }
#undef ACCUM
  float4 outv; outv.x=a0; outv.y=a1; outv.z=a2; outv.w=a3;
  *(float4*)(D + (size_t)img*HW + (size_t)y*W + x0) = outv;
}

// -------- vertical 51-tap blur + clip + soft-dice partial sums (gt,pr pair) --------
#define VTW 64
#define VTH 64
#define VLH (VTH + 2*BORDER)   // 114
__global__ __launch_bounds__(256)
void blur_v_dice_kernel(const float* __restrict__ D, double* __restrict__ sums)
{
  __shared__ float gts[VLH*VTW];
  __shared__ float prs[VLH*VTW];
  __shared__ double rbuf[12];
  const int b = blockIdx.z;
  const int gy0 = blockIdx.y * VTH;
  const int gx0 = blockIdx.x * VTW;
  const int tid = threadIdx.x;
  const float* gsrc = D + (size_t)b*HW;
  const float* psrc = D + (size_t)(b+NB)*HW;
  for (int i = tid; i < VLH*VTW; i += 256) {
    int r = i >> 6, c = i & 63;
    int gy = gy0 - BORDER + r;
    float gv = 0.f, pv = 0.f;
    if (gy >= 0 && gy < H) { int a = gy*W + gx0 + c; gv = gsrc[a]; pv = psrc[a]; }
    gts[i] = gv; prs[i] = pv;
  }
  __syncthreads();
  const int c  = tid & 63;
  const int r0 = (tid >> 6) * 16;   // 16 consecutive output rows per thread
  float ag[16], ap[16];
  #pragma unroll
  for (int j = 0; j < 16; ++j) { ag[j] = 0.f; ap[j] = 0.f; }
  #pragma unroll
  for (int t = 0; t < 16 + KLEN - 1; ++t) {   // sliding reuse: 66 loads -> 16*51 FMAs
    float vg = gts[(r0 + t)*VTW + c];
    float vp = prs[(r0 + t)*VTW + c];
    #pragma unroll
    for (int j = 0; j < 16; ++j) {
      int k = t - j;
      if (k >= 0 && k < KLEN) { ag[j] += vg * GW[k]; ap[j] += vp * GW[k]; }
    }
  }
  double sgp = 0.0, sgg = 0.0, spp = 0.0;
  #pragma unroll
  for (int j = 0; j < 16; ++j) {
    float a = fminf(fmaxf(ag[j], 0.f), 1.f);
    float p = fminf(fmaxf(ap[j], 0.f), 1.f);
    sgp += (double)(a*p); sgg += (double)(a*a); spp += (double)(p*p);
  }
  #pragma unroll
  for (int off = 32; off > 0; off >>= 1) {
    sgp += __shfl_down(sgp, off);
    sgg += __shfl_down(sgg, off);
    spp += __shfl_down(spp, off);
  }
  int lane = tid & 63, wv = tid >> 6;
  if (lane == 0) { rbuf[wv] = sgp; rbuf[4+wv] = sgg; rbuf[8+wv] = spp; }
  __syncthreads();
  if (tid == 0) {
    double a  = rbuf[0]+rbuf[1]+rbuf[2]+rbuf[3];
    double g2 = rbuf[4]+rbuf[5]+rbuf[6]+rbuf[7];
    double p2 = rbuf[8]+rbuf[9]+rbuf[10]+rbuf[11];
    atomicAdd(&sums[b],        a);
    atomicAdd(&sums[NB+b],     g2);
    atomicAdd(&sums[2*NB+b],   p2);
  }
}

__global__ void zero_sums_kernel(double* sums) {
  int t = threadIdx.x;
  if (t < 3*NB) sums[t] = 0.0;
}

__global__ void final_kernel(const double* __restrict__ sums, float* __restrict__ out) {
  if (threadIdx.x == 0) {
    double acc = 0.0;
    for (int b = 0; b < NB; ++b) {
      double num = 2.0*sums[b] + 1e-6;
      double den = sums[NB+b] + sums[2*NB+b] + 1e-6;
      acc += 1.0 - num/den;
    }
    out[0] = (float)(acc / (double)NB);
  }
}

extern "C" void kernel_launch(void* const* d_in, const int* in_sizes, int n_in,
                              void* d_out, int out_size, void* d_ws, size_t ws_size,
                              hipStream_t stream)
{
  (void)in_sizes; (void)n_in; (void)out_size; (void)ws_size;
  const float* pred = (const float*)d_in[0];   // (8,2,1024,1024) f32
  const float* targ = (const float*)d_in[1];   // (8,1024,1024) f32
  float* out = (float*)d_out;

  float* Ybuf = (float*)d_ws;                        // 16*HW floats (img carry / blur tmp)
  float* Sbuf = Ybuf + (size_t)NIMG*HW;              // 16*HW floats (skel state)
  double* sums = (double*)(Sbuf + (size_t)NIMG*HW);  // 24 doubles

  dim3 pg(16, 16, NIMG);
  hipLaunchKernelGGL(zero_sums_kernel, dim3(1), dim3(64), 0, stream, sums);
  // units 0-6 (init: s=delta0), writes Y=I_7 and S carry
  hipLaunchKernelGGL((skel_kernel<7,true,true>), pg, dim3(512), 0, stream,
                     (const float*)nullptr, pred, targ, Ybuf, Sbuf);
  // units 7-10, final skel into Sbuf
  hipLaunchKernelGGL((skel_kernel<4,false,false>), pg, dim3(512), 0, stream,
                     Ybuf, (const float*)nullptr, (const float*)nullptr,
                     (float*)nullptr, Sbuf);
  // Gaussian border: horizontal then vertical(+dice partial sums)
  hipLaunchKernelGGL(blur_h_kernel, dim3(H, NIMG), dim3(256), 0, stream, Sbuf, Ybuf);
  hipLaunchKernelGGL(blur_v_dice_kernel, dim3(W/VTW, H/VTH, NB), dim3(256), 0, stream, Ybuf, sums);
  hipLaunchKernelGGL(final_kernel, dim3(1), dim3(64), 0, stream, sums, out);
}

// Round 5
// 300.870 us; speedup vs baseline: 3.4244x; 1.2440x over previous
//
#include <hip/hip_runtime.h>

// ---------------- problem constants ----------------
#define H 1024
#define W 1024
#define HW (H*W)
#define NB 8            // batch
#define NIMG 16         // gt batch (0..7) + pred-fg batch (8..15)
#define BORDER 25
#define KLEN 51

// Unnormalized Gaussian weights g[k] = exp(-(k-25)^2/200), k=0..50 (sigma=10).
__device__ __constant__ float GW[KLEN] = {
  0.04393693f, 0.05613476f, 0.07100535f, 0.08892162f, 0.11025053f,
  0.13533528f, 0.16447446f, 0.19789869f, 0.23574608f, 0.27803730f,
  0.32465247f, 0.37531110f, 0.42955736f, 0.48675226f, 0.54607442f,
  0.60653066f, 0.66697681f, 0.72614904f, 0.78270454f, 0.83527021f,
  0.88249690f, 0.92311635f, 0.95599748f, 0.98019867f, 0.99501248f,
  1.00000000f,
  0.99501248f, 0.98019867f, 0.95599748f, 0.92311635f, 0.88249690f,
  0.83527021f, 0.78270454f, 0.72614904f, 0.66697681f, 0.60653066f,
  0.54607442f, 0.48675226f, 0.42955736f, 0.37531110f, 0.32465247f,
  0.27803730f, 0.23574608f, 0.19789869f, 0.16447446f, 0.13533528f,
  0.11025053f, 0.08892162f, 0.07100535f, 0.05613476f, 0.04393693f
};

__device__ inline float m3n(float a,float b,float c){return fminf(fminf(a,b),c);}
__device__ inline float m3x(float a,float b,float c){return fmaxf(fmaxf(a,b),c);}

__device__ inline float4 hmin4(float4 C){
  float Lw = __shfl_up(C.w, 1, 32);     // left neighbor f4's .w
  float Rx = __shfl_down(C.x, 1, 32);   // right neighbor f4's .x
  float4 h;
  h.x=m3n(Lw ,C.x,C.y); h.y=m3n(C.x,C.y,C.z);
  h.z=m3n(C.y,C.z,C.w); h.w=m3n(C.z,C.w,Rx );
  return h;
}
__device__ inline float4 hmax4(float4 C){
  float Lw = __shfl_up(C.w, 1, 32);
  float Rx = __shfl_down(C.x, 1, 32);
  float4 h;
  h.x=m3x(Lw ,C.x,C.y); h.y=m3x(C.x,C.y,C.z);
  h.z=m3x(C.y,C.z,C.w); h.w=m3x(C.z,C.w,Rx );
  return h;
}
__device__ inline float4 vmin3(float4 a,float4 b,float4 c){
  float4 o; o.x=m3n(a.x,b.x,c.x); o.y=m3n(a.y,b.y,c.y);
            o.z=m3n(a.z,b.z,c.z); o.w=m3n(a.w,b.w,c.w); return o;
}
__device__ inline float4 vmax3(float4 a,float4 b,float4 c){
  float4 o; o.x=m3x(a.x,b.x,c.x); o.y=m3x(a.y,b.y,c.y);
            o.z=m3x(a.z,b.z,c.z); o.w=m3x(a.w,b.w,c.w); return o;
}
__device__ inline float4 msk4(float4 e, bool v){
  constexpr float NINF = -__builtin_huge_valf();
  float4 o; o.x=v?e.x:NINF; o.y=v?e.y:NINF; o.z=v?e.z:NINF; o.w=v?e.w:NINF;
  return o;
}

// Single-launch register-resident fused skeletonize: all 11 units.
// Buffer: 32 f4 (128 px) x 96 rows; center px/rows [12,116)x[12,84) -> 104x72.
// 512 threads = 16 groups x 32 lanes; group g owns rows [6g, 6g+6) in regs.
// Validity: erode/dilate invalidate 1 px per side per pass from the tile edge
// (shuffles deliver true neighbors in the interior); 11 erodes + 1 dilate
// = 12 px <= halo 12. Unit u: I_{u+1}=erode(I_u); delta=relu(I_u -
// dilate(mask(I_{u+1}))); s += relu(d - s*d) (s=d at u=0). +inf padding ==
// valid-only min; mask makes dilate valid-only (exact vs reference).
__global__ __launch_bounds__(512, 4)
void skel11_kernel(const float* __restrict__ pred, const float* __restrict__ targ,
                   float* __restrict__ S)
{
  constexpr float PINF = __builtin_huge_valf();
  __shared__ float4 Xch[2][32][32];   // [slot][2 boundary rows x 16 groups][f4 col]

  const int img = blockIdx.z;
  const int bx = blockIdx.x, by = blockIdx.y;
  const int gx0 = bx*104 - 12, gy0 = by*72 - 12;
  const int tid = threadIdx.x;
  const int g = tid >> 5;             // 16 row-groups
  const int j = tid & 31;             // f4-col
  const int R0 = 6*g;
  const int gxb = gx0 + 4*j;
  const bool xok = ((unsigned)gxb < (unsigned)W);
  const bool cenj = (j >= 3) && (j < 29);

  float4 I[6], s[6];
  bool yok[6];

  // ---- load 6 rows (OOB = +inf, the min identity); softmax fg for imgs 8-15 ----
  #pragma unroll
  for (int k=0;k<6;++k) {
    int gy = gy0 + R0 + k;
    yok[k] = ((unsigned)gy < (unsigned)H);
    float4 v = make_float4(PINF,PINF,PINF,PINF);
    if (yok[k] && xok) {
      size_t off = (size_t)gy*(W/4) + (gxb>>2);
      if (img < NB) {
        v = ((const float4*)targ)[(size_t)img*(HW/4)+off];
      } else {
        int b2 = img - NB;
        float4 p0 = ((const float4*)pred)[(size_t)(2*b2  )*(HW/4)+off];
        float4 p1 = ((const float4*)pred)[(size_t)(2*b2+1)*(HW/4)+off];
        v.x = 1.0f/(1.0f + expf(p0.x - p1.x));
        v.y = 1.0f/(1.0f + expf(p0.y - p1.y));
        v.z = 1.0f/(1.0f + expf(p0.z - p1.z));
        v.w = 1.0f/(1.0f + expf(p0.w - p1.w));
      }
    }
    I[k] = v;
  }

  for (int u=0; u<11; ++u) {
    // ---- erode: H-min via shuffles; V-min with LDS boundary-row exchange ----
    float4 h[6];
    #pragma unroll
    for (int k=0;k<6;++k) h[k] = hmin4(I[k]);
    Xch[0][2*g  ][j] = h[0];
    Xch[0][2*g+1][j] = h[5];
    __syncthreads();
    float4 hm = (g>0)  ? Xch[0][2*g-1][j] : h[0];   // row R0-1 (clamp in dead margin)
    float4 hp = (g<15) ? Xch[0][2*g+2][j] : h[5];   // row R0+6
    float4 e[6];
    e[0]=vmin3(hm  ,h[0],h[1]);
    e[1]=vmin3(h[0],h[1],h[2]);
    e[2]=vmin3(h[1],h[2],h[3]);
    e[3]=vmin3(h[2],h[3],h[4]);
    e[4]=vmin3(h[3],h[4],h[5]);
    e[5]=vmin3(h[4],h[5],hp  );

    // ---- dilate of masked I_{u+1} (outside image -> -inf) ----
    float4 x[6];
    #pragma unroll
    for (int k=0;k<6;++k) x[k] = hmax4(msk4(e[k], xok && yok[k]));
    Xch[1][2*g  ][j] = x[0];
    Xch[1][2*g+1][j] = x[5];
    __syncthreads();
    float4 xm = (g>0)  ? Xch[1][2*g-1][j] : x[0];
    float4 xp = (g<15) ? Xch[1][2*g+2][j] : x[5];

    // ---- delta + skel update + commit I_{u+1} ----
    #pragma unroll
    for (int k=0;k<6;++k) {
      float4 dl = vmax3((k==0)?xm:x[k-1], x[k], (k==5)?xp:x[k+1]);
      float dx = fmaxf(I[k].x-dl.x,0.f), dy = fmaxf(I[k].y-dl.y,0.f);
      float dz = fmaxf(I[k].z-dl.z,0.f), dw = fmaxf(I[k].w-dl.w,0.f);
      if (u == 0) {
        s[k] = make_float4(dx,dy,dz,dw);
      } else {
        s[k].x += fmaxf(dx - s[k].x*dx, 0.f);
        s[k].y += fmaxf(dy - s[k].y*dy, 0.f);
        s[k].z += fmaxf(dz - s[k].z*dz, 0.f);
        s[k].w += fmaxf(dw - s[k].w*dw, 0.f);
      }
      I[k] = e[k];
    }
  }

  // ---- write back skel (center, clipped to image) ----
  if (cenj) {
    #pragma unroll
    for (int k=0;k<6;++k) {
      int rr = R0+k;
      if (rr >= 12 && rr < 84) {
        int gy = gy0 + rr;          // >= 0 since rr >= 12
        if (gy < H && gxb < W)
          ((float4*)S)[(size_t)img*(HW/4) + (size_t)gy*(W/4) + (gxb>>2)] = s[k];
      }
    }
  }
}

// -------- horizontal 51-tap blur (zero padding), 4 outputs/thread --------
__global__ __launch_bounds__(256)
void blur_h_kernel(const float* __restrict__ Sin, float* __restrict__ D)
{
  __shared__ __align__(16) float row[1080];   // [-25, 1024+25) padded
  const int img = blockIdx.y;
  const int y = blockIdx.x;
  const int tid = threadIdx.x;
  const float* src = Sin + (size_t)img*HW + (size_t)y*W;
  for (int i = tid; i < 1080; i += 256) {
    int x = i - BORDER;
    row[i] = (x >= 0 && x < W) ? src[x] : 0.0f;
  }
  __syncthreads();
  const int x0 = tid * 4;
  float a0=0.f, a1=0.f, a2=0.f, a3=0.f;
  const float4* rp = (const float4*)row;
#define ACCUM(val, idx)                                                     \
  { if ((idx)   >= 0 && (idx)   <= 50) a0 += (val) * GW[(idx)];             \
    if ((idx)-1 >= 0 && (idx)-1 <= 50) a1 += (val) * GW[(idx)-1];           \
    if ((idx)-2 >= 0 && (idx)-2 <= 50) a2 += (val) * GW[(idx)-2];           \
    if ((idx)-3 >= 0 && (idx)-3 <= 50) a3 += (val) * GW[(idx)-3]; }
  #pragma unroll
  for (int t4 = 0; t4 < 14; ++t4) {
    float4 v = rp[tid + t4];
    const int base = 4*t4;
    ACCUM(v.x, base+0) ACCUM(v.y, base+1) ACCUM(v.z, base+2) ACCUM(v.w, base+3)
  }
#undef ACCUM
  float4 outv; outv.x=a0; outv.y=a1; outv.z=a2; outv.w=a3;
  *(float4*)(D + (size_t)img*HW + (size_t)y*W + x0) = outv;
}

// -------- vertical 51-tap blur + clip + soft-dice partial sums (gt,pr pair) --------
#define VTW 64
#define VTH 64
#define VLH (VTH + 2*BORDER)   // 114
__global__ __launch_bounds__(256)
void blur_v_dice_kernel(const float* __restrict__ D, double* __restrict__ sums)
{
  __shared__ float gts[VLH*VTW];
  __shared__ float prs[VLH*VTW];
  __shared__ double rbuf[12];
  const int b = blockIdx.z;
  const int gy0 = blockIdx.y * VTH;
  const int gx0 = blockIdx.x * VTW;
  const int tid = threadIdx.x;
  const float* gsrc = D + (size_t)b*HW;
  const float* psrc = D + (size_t)(b+NB)*HW;
  for (int i = tid; i < VLH*VTW; i += 256) {
    int r = i >> 6, c = i & 63;
    int gy = gy0 - BORDER + r;
    float gv = 0.f, pv = 0.f;
    if (gy >= 0 && gy < H) { int a = gy*W + gx0 + c; gv = gsrc[a]; pv = psrc[a]; }
    gts[i] = gv; prs[i] = pv;
  }
  __syncthreads();
  const int c  = tid & 63;
  const int r0 = (tid >> 6) * 16;   // 16 consecutive output rows per thread
  float ag[16], ap[16];
  #pragma unroll
  for (int j = 0; j < 16; ++j) { ag[j] = 0.f; ap[j] = 0.f; }
  #pragma unroll
  for (int t = 0; t < 16 + KLEN - 1; ++t) {   // sliding reuse: 66 loads -> 16*51 FMAs
    float vg = gts[(r0 + t)*VTW + c];
    float vp = prs[(r0 + t)*VTW + c];
    #pragma unroll
    for (int j = 0; j < 16; ++j) {
      int k = t - j;
      if (k >= 0 && k < KLEN) { ag[j] += vg * GW[k]; ap[j] += vp * GW[k]; }
    }
  }
  double sgp = 0.0, sgg = 0.0, spp = 0.0;
  #pragma unroll
  for (int j = 0; j < 16; ++j) {
    float a = fminf(fmaxf(ag[j], 0.f), 1.f);
    float p = fminf(fmaxf(ap[j], 0.f), 1.f);
    sgp += (double)(a*p); sgg += (double)(a*a); spp += (double)(p*p);
  }
  #pragma unroll
  for (int off = 32; off > 0; off >>= 1) {
    sgp += __shfl_down(sgp, off);
    sgg += __shfl_down(sgg, off);
    spp += __shfl_down(spp, off);
  }
  int lane = tid & 63, wv = tid >> 6;
  if (lane == 0) { rbuf[wv] = sgp; rbuf[4+wv] = sgg; rbuf[8+wv] = spp; }
  __syncthreads();
  if (tid == 0) {
    double a  = rbuf[0]+rbuf[1]+rbuf[2]+rbuf[3];
    double g2 = rbuf[4]+rbuf[5]+rbuf[6]+rbuf[7];
    double p2 = rbuf[8]+rbuf[9]+rbuf[10]+rbuf[11];
    atomicAdd(&sums[b],        a);
    atomicAdd(&sums[NB+b],     g2);
    atomicAdd(&sums[2*NB+b],   p2);
  }
}

__global__ void zero_sums_kernel(double* sums) {
  int t = threadIdx.x;
  if (t < 3*NB) sums[t] = 0.0;
}

__global__ void final_kernel(const double* __restrict__ sums, float* __restrict__ out) {
  if (threadIdx.x == 0) {
    double acc = 0.0;
    for (int b = 0; b < NB; ++b) {
      double num = 2.0*sums[b] + 1e-6;
      double den = sums[NB+b] + sums[2*NB+b] + 1e-6;
      acc += 1.0 - num/den;
    }
    out[0] = (float)(acc / (double)NB);
  }
}

extern "C" void kernel_launch(void* const* d_in, const int* in_sizes, int n_in,
                              void* d_out, int out_size, void* d_ws, size_t ws_size,
                              hipStream_t stream)
{
  (void)in_sizes; (void)n_in; (void)out_size; (void)ws_size;
  const float* pred = (const float*)d_in[0];   // (8,2,1024,1024) f32
  const float* targ = (const float*)d_in[1];   // (8,1024,1024) f32
  float* out = (float*)d_out;

  float* Ybuf = (float*)d_ws;                        // 16*HW floats (blur tmp)
  float* Sbuf = Ybuf + (size_t)NIMG*HW;              // 16*HW floats (skel)
  double* sums = (double*)(Sbuf + (size_t)NIMG*HW);  // 24 doubles

  hipLaunchKernelGGL(zero_sums_kernel, dim3(1), dim3(64), 0, stream, sums);
  // all 11 skeletonize units in one launch (center 104x72 per block)
  hipLaunchKernelGGL(skel11_kernel, dim3(10, 15, NIMG), dim3(512), 0, stream,
                     pred, targ, Sbuf);
  // Gaussian border: horizontal then vertical(+dice partial sums)
  hipLaunchKernelGGL(blur_h_kernel, dim3(H, NIMG), dim3(256), 0, stream, Sbuf, Ybuf);
  hipLaunchKernelGGL(blur_v_dice_kernel, dim3(W/VTW, H/VTH, NB), dim3(256), 0, stream, Ybuf, sums);
  hipLaunchKernelGGL(final_kernel, dim3(1), dim3(64), 0, stream, sums, out);
}

// Round 6
// 281.913 us; speedup vs baseline: 3.6546x; 1.0672x over previous
//
#include <hip/hip_runtime.h>

// ---------------- problem constants ----------------
#define H 1024
#define W 1024
#define HW (H*W)
#define NB 8            // batch
#define NIMG 16         // gt batch (0..7) + pred-fg batch (8..15)
#define BORDER 25
#define KLEN 51

// Unnormalized Gaussian weights g[k] = exp(-(k-25)^2/200), k=0..50 (sigma=10).
__device__ __constant__ float GW[KLEN] = {
  0.04393693f, 0.05613476f, 0.07100535f, 0.08892162f, 0.11025053f,
  0.13533528f, 0.16447446f, 0.19789869f, 0.23574608f, 0.27803730f,
  0.32465247f, 0.37531110f, 0.42955736f, 0.48675226f, 0.54607442f,
  0.60653066f, 0.66697681f, 0.72614904f, 0.78270454f, 0.83527021f,
  0.88249690f, 0.92311635f, 0.95599748f, 0.98019867f, 0.99501248f,
  1.00000000f,
  0.99501248f, 0.98019867f, 0.95599748f, 0.92311635f, 0.88249690f,
  0.83527021f, 0.78270454f, 0.72614904f, 0.66697681f, 0.60653066f,
  0.54607442f, 0.48675226f, 0.42955736f, 0.37531110f, 0.32465247f,
  0.27803730f, 0.23574608f, 0.19789869f, 0.16447446f, 0.13533528f,
  0.11025053f, 0.08892162f, 0.07100535f, 0.05613476f, 0.04393693f
};

__device__ inline float m3n(float a,float b,float c){return fminf(fminf(a,b),c);}
__device__ inline float m3x(float a,float b,float c){return fmaxf(fmaxf(a,b),c);}

// DPP wave shifts (VALU, no DS pipe): lane i <- lane i-/+1; boundary lanes keep own.
// Crossing the half-wave boundary only corrupts the j=0/31 halo cols (same lanes
// the old __shfl clamp corrupted) — covered by the 12px invalidation budget.
__device__ inline float dpp_shr1(float x){   // lane i <- lane i-1  (shfl_up)
  return __int_as_float(__builtin_amdgcn_update_dpp(
      __float_as_int(x), __float_as_int(x), 0x138, 0xf, 0xf, false));
}
__device__ inline float dpp_shl1(float x){   // lane i <- lane i+1  (shfl_down)
  return __int_as_float(__builtin_amdgcn_update_dpp(
      __float_as_int(x), __float_as_int(x), 0x130, 0xf, 0xf, false));
}

__device__ inline float4 hmin4(float4 C){
  float Lw = dpp_shr1(C.w);    // left neighbor f4's .w
  float Rx = dpp_shl1(C.x);    // right neighbor f4's .x
  float4 h;
  h.x=m3n(Lw ,C.x,C.y); h.y=m3n(C.x,C.y,C.z);
  h.z=m3n(C.y,C.z,C.w); h.w=m3n(C.z,C.w,Rx );
  return h;
}
__device__ inline float4 hmax4(float4 C){
  float Lw = dpp_shr1(C.w);
  float Rx = dpp_shl1(C.x);
  float4 h;
  h.x=m3x(Lw ,C.x,C.y); h.y=m3x(C.x,C.y,C.z);
  h.z=m3x(C.y,C.z,C.w); h.w=m3x(C.z,C.w,Rx );
  return h;
}
__device__ inline float4 vmin3(float4 a,float4 b,float4 c){
  float4 o; o.x=m3n(a.x,b.x,c.x); o.y=m3n(a.y,b.y,c.y);
            o.z=m3n(a.z,b.z,c.z); o.w=m3n(a.w,b.w,c.w); return o;
}
__device__ inline float4 vmax3(float4 a,float4 b,float4 c){
  float4 o; o.x=m3x(a.x,b.x,c.x); o.y=m3x(a.y,b.y,c.y);
            o.z=m3x(a.z,b.z,c.z); o.w=m3x(a.w,b.w,c.w); return o;
}
__device__ inline float4 msk4(float4 e, bool v){
  constexpr float NINF = -__builtin_huge_valf();
  float4 o; o.x=v?e.x:NINF; o.y=v?e.y:NINF; o.z=v?e.z:NINF; o.w=v?e.w:NINF;
  return o;
}

// Single-launch register-resident fused skeletonize: all 11 units.
// Buffer: 32 f4 (128 px) x 96 rows; center px/rows [12,116)x[12,84) -> 104x72.
// 512 threads = 16 groups x 32 lanes; group g owns rows [6g, 6g+6) in regs.
// Horizontal 3-taps via DPP wave-shifts; vertical group-boundary rows exchanged
// through a tiny LDS buffer (contiguous b128, 2-way-aliased = free).
// Unit u: I_{u+1}=erode(I_u); delta=relu(I_u - dilate(mask(I_{u+1})));
// s += relu(d - s*d) (s=d at u=0). +inf padding == valid-only min; mask makes
// dilate valid-only (exact vs reference). 11 erodes + 1 dilate = 12 px <= halo 12.
__global__ __launch_bounds__(512, 4)
void skel11_kernel(const float* __restrict__ pred, const float* __restrict__ targ,
                   float* __restrict__ S)
{
  constexpr float PINF = __builtin_huge_valf();
  __shared__ float4 Xch[2][32][32];   // [slot][2 boundary rows x 16 groups][f4 col]

  const int img = blockIdx.z;
  const int bx = blockIdx.x, by = blockIdx.y;
  const int gx0 = bx*104 - 12, gy0 = by*72 - 12;
  const int tid = threadIdx.x;
  const int g = tid >> 5;             // 16 row-groups
  const int j = tid & 31;             // f4-col
  const int R0 = 6*g;
  const int gxb = gx0 + 4*j;
  const bool xok = ((unsigned)gxb < (unsigned)W);
  const bool cenj = (j >= 3) && (j < 29);
  const bool allok = (gx0 >= 0) && (gx0 + 128 <= W) && (gy0 >= 0) && (gy0 + 96 <= H);

  float4 I[6], s[6];
  bool yok[6];

  // ---- load 6 rows (OOB = +inf, the min identity); softmax fg for imgs 8-15 ----
  #pragma unroll
  for (int k=0;k<6;++k) {
    int gy = gy0 + R0 + k;
    yok[k] = ((unsigned)gy < (unsigned)H);
    float4 v = make_float4(PINF,PINF,PINF,PINF);
    if (yok[k] && xok) {
      size_t off = (size_t)gy*(W/4) + (gxb>>2);
      if (img < NB) {
        v = ((const float4*)targ)[(size_t)img*(HW/4)+off];
      } else {
        int b2 = img - NB;
        float4 p0 = ((const float4*)pred)[(size_t)(2*b2  )*(HW/4)+off];
        float4 p1 = ((const float4*)pred)[(size_t)(2*b2+1)*(HW/4)+off];
        v.x = 1.0f/(1.0f + expf(p0.x - p1.x));
        v.y = 1.0f/(1.0f + expf(p0.y - p1.y));
        v.z = 1.0f/(1.0f + expf(p0.z - p1.z));
        v.w = 1.0f/(1.0f + expf(p0.w - p1.w));
      }
    }
    I[k] = v;
  }

  for (int u=0; u<11; ++u) {
    // ---- erode: H-min via DPP; V-min with LDS boundary-row exchange ----
    float4 h[6];
    #pragma unroll
    for (int k=0;k<6;++k) h[k] = hmin4(I[k]);
    Xch[0][2*g  ][j] = h[0];
    Xch[0][2*g+1][j] = h[5];
    __syncthreads();
    float4 hm = (g>0)  ? Xch[0][2*g-1][j] : h[0];   // row R0-1 (clamp in dead margin)
    float4 hp = (g<15) ? Xch[0][2*g+2][j] : h[5];   // row R0+6
    float4 e[6];
    e[0]=vmin3(hm  ,h[0],h[1]);
    e[1]=vmin3(h[0],h[1],h[2]);
    e[2]=vmin3(h[1],h[2],h[3]);
    e[3]=vmin3(h[2],h[3],h[4]);
    e[4]=vmin3(h[3],h[4],h[5]);
    e[5]=vmin3(h[4],h[5],hp  );

    // ---- dilate of masked I_{u+1} (outside image -> -inf); interior skips mask ----
    float4 x[6];
    if (allok) {
      #pragma unroll
      for (int k=0;k<6;++k) x[k] = hmax4(e[k]);
    } else {
      #pragma unroll
      for (int k=0;k<6;++k) x[k] = hmax4(msk4(e[k], xok && yok[k]));
    }
    Xch[1][2*g  ][j] = x[0];
    Xch[1][2*g+1][j] = x[5];
    __syncthreads();
    float4 xm = (g>0)  ? Xch[1][2*g-1][j] : x[0];
    float4 xp = (g<15) ? Xch[1][2*g+2][j] : x[5];

    // ---- delta + skel update + commit I_{u+1} ----
    #pragma unroll
    for (int k=0;k<6;++k) {
      float4 dl = vmax3((k==0)?xm:x[k-1], x[k], (k==5)?xp:x[k+1]);
      float dx = fmaxf(I[k].x-dl.x,0.f), dy = fmaxf(I[k].y-dl.y,0.f);
      float dz = fmaxf(I[k].z-dl.z,0.f), dw = fmaxf(I[k].w-dl.w,0.f);
      if (u == 0) {
        s[k] = make_float4(dx,dy,dz,dw);
      } else {
        s[k].x += fmaxf(dx - s[k].x*dx, 0.f);
        s[k].y += fmaxf(dy - s[k].y*dy, 0.f);
        s[k].z += fmaxf(dz - s[k].z*dz, 0.f);
        s[k].w += fmaxf(dw - s[k].w*dw, 0.f);
      }
      I[k] = e[k];
    }
  }

  // ---- write back skel (center, clipped to image) ----
  if (cenj) {
    #pragma unroll
    for (int k=0;k<6;++k) {
      int rr = R0+k;
      if (rr >= 12 && rr < 84) {
        int gy = gy0 + rr;          // >= 0 since rr >= 12
        if (gy < H && gxb < W)
          ((float4*)S)[(size_t)img*(HW/4) + (size_t)gy*(W/4) + (gxb>>2)] = s[k];
      }
    }
  }
}

// -------- horizontal 51-tap blur (zero padding), 4 outputs/thread --------
__global__ __launch_bounds__(256)
void blur_h_kernel(const float* __restrict__ Sin, float* __restrict__ D)
{
  __shared__ __align__(16) float row[1080];   // [-25, 1024+25) padded
  const int img = blockIdx.y;
  const int y = blockIdx.x;
  const int tid = threadIdx.x;
  const float* src = Sin + (size_t)img*HW + (size_t)y*W;
  for (int i = tid; i < 1080; i += 256) {
    int x = i - BORDER;
    row[i] = (x >= 0 && x < W) ? src[x] : 0.0f;
  }
  __syncthreads();
  const int x0 = tid * 4;
  float a0=0.f, a1=0.f, a2=0.f, a3=0.f;
  const float4* rp = (const float4*)row;
#define ACCUM(val, idx)                                                     \
  { if ((idx)   >= 0 && (idx)   <= 50) a0 += (val) * GW[(idx)];             \
    if ((idx)-1 >= 0 && (idx)-1 <= 50) a1 += (val) * GW[(idx)-1];           \
    if ((idx)-2 >= 0 && (idx)-2 <= 50) a2 += (val) * GW[(idx)-2];           \
    if ((idx)-3 >= 0 && (idx)-3 <= 50) a3 += (val) * GW[(idx)-3]; }
  #pragma unroll
  for (int t4 = 0; t4 < 14; ++t4) {
    float4 v = rp[tid + t4];
    const int base = 4*t4;
    ACCUM(v.x, base+0) ACCUM(v.y, base+1) ACCUM(v.z, base+2) ACCUM(v.w, base+3)
  }
#undef ACCUM
  float4 outv; outv.x=a0; outv.y=a1; outv.z=a2; outv.w=a3;
  *(float4*)(D + (size_t)img*HW + (size_t)y*W + x0) = outv;
}

// -------- vertical 51-tap blur + clip + soft-dice partial sums (gt,pr pair) --------
#define VTW 64
#define VTH 64
#define VLH (VTH + 2*BORDER)   // 114
__global__ __launch_bounds__(256)
void blur_v_dice_kernel(const float* __restrict__ D, double* __restrict__ sums)
{
  __shared__ float gts[VLH*VTW];
  __shared__ float prs[VLH*VTW];
  __shared__ double rbuf[12];
  const int b = blockIdx.z;
  const int gy0 = blockIdx.y * VTH;
  const int gx0 = blockIdx.x * VTW;
  const int tid = threadIdx.x;
  const float* gsrc = D + (size_t)b*HW;
  const float* psrc = D + (size_t)(b+NB)*HW;
  for (int i = tid; i < VLH*VTW; i += 256) {
    int r = i >> 6, c = i & 63;
    int gy = gy0 - BORDER + r;
    float gv = 0.f, pv = 0.f;
    if (gy >= 0 && gy < H) { int a = gy*W + gx0 + c; gv = gsrc[a]; pv = psrc[a]; }
    gts[i] = gv; prs[i] = pv;
  }
  __syncthreads();
  const int c  = tid & 63;
  const int r0 = (tid >> 6) * 16;   // 16 consecutive output rows per thread
  float ag[16], ap[16];
  #pragma unroll
  for (int j = 0; j < 16; ++j) { ag[j] = 0.f; ap[j] = 0.f; }
  #pragma unroll
  for (int t = 0; t < 16 + KLEN - 1; ++t) {   // sliding reuse: 66 loads -> 16*51 FMAs
    float vg = gts[(r0 + t)*VTW + c];
    float vp = prs[(r0 + t)*VTW + c];
    #pragma unroll
    for (int j = 0; j < 16; ++j) {
      int k = t - j;
      if (k >= 0 && k < KLEN) { ag[j] += vg * GW[k]; ap[j] += vp * GW[k]; }
    }
  }
  double sgp = 0.0, sgg = 0.0, spp = 0.0;
  #pragma unroll
  for (int j = 0; j < 16; ++j) {
    float a = fminf(fmaxf(ag[j], 0.f), 1.f);
    float p = fminf(fmaxf(ap[j], 0.f), 1.f);
    sgp += (double)(a*p); sgg += (double)(a*a); spp += (double)(p*p);
  }
  #pragma unroll
  for (int off = 32; off > 0; off >>= 1) {
    sgp += __shfl_down(sgp, off);
    sgg += __shfl_down(sgg, off);
    spp += __shfl_down(spp, off);
  }
  int lane = tid & 63, wv = tid >> 6;
  if (lane == 0) { rbuf[wv] = sgp; rbuf[4+wv] = sgg; rbuf[8+wv] = spp; }
  __syncthreads();
  if (tid == 0) {
    double a  = rbuf[0]+rbuf[1]+rbuf[2]+rbuf[3];
    double g2 = rbuf[4]+rbuf[5]+rbuf[6]+rbuf[7];
    double p2 = rbuf[8]+rbuf[9]+rbuf[10]+rbuf[11];
    atomicAdd(&sums[b],        a);
    atomicAdd(&sums[NB+b],     g2);
    atomicAdd(&sums[2*NB+b],   p2);
  }
}

__global__ void zero_sums_kernel(double* sums) {
  int t = threadIdx.x;
  if (t < 3*NB) sums[t] = 0.0;
}

__global__ void final_kernel(const double* __restrict__ sums, float* __restrict__ out) {
  if (threadIdx.x == 0) {
    double acc = 0.0;
    for (int b = 0; b < NB; ++b) {
      double num = 2.0*sums[b] + 1e-6;
      double den = sums[NB+b] + sums[2*NB+b] + 1e-6;
      acc += 1.0 - num/den;
    }
    out[0] = (float)(acc / (double)NB);
  }
}

extern "C" void kernel_launch(void* const* d_in, const int* in_sizes, int n_in,
                              void* d_out, int out_size, void* d_ws, size_t ws_size,
                              hipStream_t stream)
{
  (void)in_sizes; (void)n_in; (void)out_size; (void)ws_size;
  const float* pred = (const float*)d_in[0];   // (8,2,1024,1024) f32
  const float* targ = (const float*)d_in[1];   // (8,1024,1024) f32
  float* out = (float*)d_out;

  float* Ybuf = (float*)d_ws;                        // 16*HW floats (blur tmp)
  float* Sbuf = Ybuf + (size_t)NIMG*HW;              // 16*HW floats (skel)
  double* sums = (double*)(Sbuf + (size_t)NIMG*HW);  // 24 doubles

  hipLaunchKernelGGL(zero_sums_kernel, dim3(1), dim3(64), 0, stream, sums);
  // all 11 skeletonize units in one launch (center 104x72 per block)
  hipLaunchKernelGGL(skel11_kernel, dim3(10, 15, NIMG), dim3(512), 0, stream,
                     pred, targ, Sbuf);
  // Gaussian border: horizontal then vertical(+dice partial sums)
  hipLaunchKernelGGL(blur_h_kernel, dim3(H, NIMG), dim3(256), 0, stream, Sbuf, Ybuf);
  hipLaunchKernelGGL(blur_v_dice_kernel, dim3(W/VTW, H/VTH, NB), dim3(256), 0, stream, Ybuf, sums);
  hipLaunchKernelGGL(final_kernel, dim3(1), dim3(64), 0, stream, sums, out);
}

// Round 7
// 253.939 us; speedup vs baseline: 4.0572x; 1.1102x over previous
//
#include <hip/hip_runtime.h>

// ---------------- problem constants ----------------
#define H 1024
#define W 1024
#define HW (H*W)
#define NB 8            // batch
#define NIMG 16         // gt batch (0..7) + pred-fg batch (8..15)
#define BORDER 25
#define KLEN 51

// Unnormalized Gaussian weights g[k] = exp(-(k-25)^2/200), k=0..50 (sigma=10).
__device__ __constant__ float GW[KLEN] = {
  0.04393693f, 0.05613476f, 0.07100535f, 0.08892162f, 0.11025053f,
  0.13533528f, 0.16447446f, 0.19789869f, 0.23574608f, 0.27803730f,
  0.32465247f, 0.37531110f, 0.42955736f, 0.48675226f, 0.54607442f,
  0.60653066f, 0.66697681f, 0.72614904f, 0.78270454f, 0.83527021f,
  0.88249690f, 0.92311635f, 0.95599748f, 0.98019867f, 0.99501248f,
  1.00000000f,
  0.99501248f, 0.98019867f, 0.95599748f, 0.92311635f, 0.88249690f,
  0.83527021f, 0.78270454f, 0.72614904f, 0.66697681f, 0.60653066f,
  0.54607442f, 0.48675226f, 0.42955736f, 0.37531110f, 0.32465247f,
  0.27803730f, 0.23574608f, 0.19789869f, 0.16447446f, 0.13533528f,
  0.11025053f, 0.08892162f, 0.07100535f, 0.05613476f, 0.04393693f
};

// Force single-instruction 3-input min/max (VOP3; all operands VGPR).
__device__ inline float m3n(float a,float b,float c){
  float d; asm("v_min3_f32 %0, %1, %2, %3" : "=v"(d) : "v"(a), "v"(b), "v"(c));
  return d;
}
__device__ inline float m3x(float a,float b,float c){
  float d; asm("v_max3_f32 %0, %1, %2, %3" : "=v"(d) : "v"(a), "v"(b), "v"(c));
  return d;
}

// Single-inst DPP wave shifts (bound_ctrl: OOB lane -> 0). The zeroed lane only
// corrupts buffer col 0 / col 127 — already invalid halo (12px budget).
__device__ inline float dpp_shr1(float x){   // lane i <- lane i-1
  return __int_as_float(__builtin_amdgcn_mov_dpp(__float_as_int(x), 0x138, 0xf, 0xf, true));
}
__device__ inline float dpp_shl1(float x){   // lane i <- lane i+1
  return __int_as_float(__builtin_amdgcn_mov_dpp(__float_as_int(x), 0x130, 0xf, 0xf, true));
}

__device__ inline float4 hmin4(float4 C){
  float Lw = dpp_shr1(C.w);
  float Rx = dpp_shl1(C.x);
  float4 h;
  h.x=m3n(Lw ,C.x,C.y); h.y=m3n(C.x,C.y,C.z);
  h.z=m3n(C.y,C.z,C.w); h.w=m3n(C.z,C.w,Rx );
  return h;
}
__device__ inline float4 hmax4(float4 C){
  float Lw = dpp_shr1(C.w);
  float Rx = dpp_shl1(C.x);
  float4 h;
  h.x=m3x(Lw ,C.x,C.y); h.y=m3x(C.x,C.y,C.z);
  h.z=m3x(C.y,C.z,C.w); h.w=m3x(C.z,C.w,Rx );
  return h;
}
__device__ inline float4 vmin3(float4 a,float4 b,float4 c){
  float4 o; o.x=m3n(a.x,b.x,c.x); o.y=m3n(a.y,b.y,c.y);
            o.z=m3n(a.z,b.z,c.z); o.w=m3n(a.w,b.w,c.w); return o;
}
__device__ inline float4 vmax3(float4 a,float4 b,float4 c){
  float4 o; o.x=m3x(a.x,b.x,c.x); o.y=m3x(a.y,b.y,c.y);
            o.z=m3x(a.z,b.z,c.z); o.w=m3x(a.w,b.w,c.w); return o;
}
__device__ inline float4 msk4(float4 e, bool v){
  constexpr float NINF = -__builtin_huge_valf();
  float4 o; o.x=v?e.x:NINF; o.y=v?e.y:NINF; o.z=v?e.z:NINF; o.w=v?e.w:NINF;
  return o;
}

// Single-launch register-resident fused skeletonize: all 11 units.
// Buffer: 32 f4 (128 px) x 96 rows; center px/rows [12,116)x[12,84) -> 104x72.
// 512 threads = 16 groups x 32 lanes; group g owns rows [6g, 6g+6) in regs.
// Wave w = groups {2w, 2w+1}. Waves 1-6 own exactly the center rows [12,84):
// only they run dilate/delta/skel-update; waves 0/7 contribute just the one
// boundary dilate row their neighbors read. Erode runs on all waves (state).
// Exchange reads use clamped indices: the clamped slot holds exactly the
// fallback value (own boundary row), so no selects are needed.
// Unit u: I_{u+1}=erode(I_u); delta=relu(I_u - dilate(mask(I_{u+1})));
// s += relu(d - s*d) (s=d at u=0). +inf padding == valid-only min; mask makes
// dilate valid-only (exact vs reference). 11 erodes + 1 dilate = 12 px <= halo 12.
__global__ __launch_bounds__(512, 4)
void skel11_kernel(const float* __restrict__ pred, const float* __restrict__ targ,
                   float* __restrict__ S, double* __restrict__ sums)
{
  constexpr float PINF = __builtin_huge_valf();
  __shared__ float4 Xch[2][32][32];   // [slot][2 boundary rows x 16 groups][f4 col]

  const int img = blockIdx.z;
  const int bx = blockIdx.x, by = blockIdx.y;

  // fold zero_sums launch into this kernel (sums consumed only by later kernels)
  if (bx==0 && by==0 && img==0 && threadIdx.x < 3*NB) sums[threadIdx.x] = 0.0;

  const int gx0 = bx*104 - 12, gy0 = by*72 - 12;
  const int tid = threadIdx.x;
  const int g = tid >> 5;             // 16 row-groups
  const int j = tid & 31;             // f4-col
  const int wid = tid >> 6;           // wave 0..7
  const int R0 = 6*g;
  const int gxb = gx0 + 4*j;
  const bool xok = ((unsigned)gxb < (unsigned)W);
  const bool cenj = (j >= 3) && (j < 29);
  const bool allok = (gx0 >= 0) && (gx0 + 128 <= W) && (gy0 >= 0) && (gy0 + 96 <= H);
  const bool cwave = (wid >= 1) && (wid <= 6);   // rows 6g+k all in [12,84)

  // clamped exchange indices (clamped slot == own boundary row == fallback)
  const int ixm = (g>0)  ? 2*g-1 : 0;
  const int ixp = (g<15) ? 2*g+2 : 31;

  float4 I[6], s[6];
  bool yok[6];

  // ---- load 6 rows (OOB = +inf, the min identity); softmax fg for imgs 8-15 ----
  #pragma unroll
  for (int k=0;k<6;++k) {
    int gy = gy0 + R0 + k;
    yok[k] = ((unsigned)gy < (unsigned)H);
    float4 v = make_float4(PINF,PINF,PINF,PINF);
    if (yok[k] && xok) {
      size_t off = (size_t)gy*(W/4) + (gxb>>2);
      if (img < NB) {
        v = ((const float4*)targ)[(size_t)img*(HW/4)+off];
      } else {
        int b2 = img - NB;
        float4 p0 = ((const float4*)pred)[(size_t)(2*b2  )*(HW/4)+off];
        float4 p1 = ((const float4*)pred)[(size_t)(2*b2+1)*(HW/4)+off];
        v.x = 1.0f/(1.0f + expf(p0.x - p1.x));
        v.y = 1.0f/(1.0f + expf(p0.y - p1.y));
        v.z = 1.0f/(1.0f + expf(p0.z - p1.z));
        v.w = 1.0f/(1.0f + expf(p0.w - p1.w));
      }
    }
    I[k] = v;
  }

  for (int u=0; u<11; ++u) {
    // ---- erode (all waves): H-min via DPP; V-min with boundary exchange ----
    float4 h[6];
    #pragma unroll
    for (int k=0;k<6;++k) h[k] = hmin4(I[k]);
    Xch[0][2*g  ][j] = h[0];
    Xch[0][2*g+1][j] = h[5];
    __syncthreads();
    float4 hm = Xch[0][ixm][j];
    float4 hp = Xch[0][ixp][j];
    float4 e[6];
    e[0]=vmin3(hm  ,h[0],h[1]);
    e[1]=vmin3(h[0],h[1],h[2]);
    e[2]=vmin3(h[1],h[2],h[3]);
    e[3]=vmin3(h[2],h[3],h[4]);
    e[4]=vmin3(h[3],h[4],h[5]);
    e[5]=vmin3(h[4],h[5],hp  );

    // ---- dilate of masked I_{u+1}: full on waves 1-6, boundary row on 0/7 ----
    float4 x[6];
    if (cwave) {
      if (allok) {
        #pragma unroll
        for (int k=0;k<6;++k) x[k] = hmax4(e[k]);
      } else {
        #pragma unroll
        for (int k=0;k<6;++k) x[k] = hmax4(msk4(e[k], xok && yok[k]));
      }
      Xch[1][2*g  ][j] = x[0];
      Xch[1][2*g+1][j] = x[5];
    } else if (wid == 0) {      // neighbors read only group1 row5 (Xch[1][3])
      float4 x5 = allok ? hmax4(e[5]) : hmax4(msk4(e[5], xok && yok[5]));
      Xch[1][2*g+1][j] = x5;
    } else {                    // wid==7: neighbors read only group14 row0 (Xch[1][28])
      float4 x0 = allok ? hmax4(e[0]) : hmax4(msk4(e[0], xok && yok[0]));
      Xch[1][2*g  ][j] = x0;
    }
    __syncthreads();

    // ---- delta + skel update (waves 1-6 only; their rows are all center) ----
    if (cwave) {
      float4 xm = Xch[1][2*g-1][j];   // g in [2,13]: indices always valid
      float4 xp = Xch[1][2*g+2][j];
      #pragma unroll
      for (int k=0;k<6;++k) {
        float4 dl = vmax3((k==0)?xm:x[k-1], x[k], (k==5)?xp:x[k+1]);
        float dx = fmaxf(I[k].x-dl.x,0.f), dy = fmaxf(I[k].y-dl.y,0.f);
        float dz = fmaxf(I[k].z-dl.z,0.f), dw = fmaxf(I[k].w-dl.w,0.f);
        if (u == 0) {
          s[k] = make_float4(dx,dy,dz,dw);
        } else {
          s[k].x += fmaxf(fmaf(-s[k].x, dx, dx), 0.f);
          s[k].y += fmaxf(fmaf(-s[k].y, dy, dy), 0.f);
          s[k].z += fmaxf(fmaf(-s[k].z, dz, dz), 0.f);
          s[k].w += fmaxf(fmaf(-s[k].w, dw, dw), 0.f);
        }
      }
    }
    #pragma unroll
    for (int k=0;k<6;++k) I[k] = e[k];
  }

  // ---- write back skel (waves 1-6, center cols, clipped to image) ----
  if (cwave && cenj && gxb < W) {
    #pragma unroll
    for (int k=0;k<6;++k) {
      int gy = gy0 + R0 + k;        // rows 12..83 of buffer -> gy >= 0
      if (gy < H)
        ((float4*)S)[(size_t)img*(HW/4) + (size_t)gy*(W/4) + (gxb>>2)] = s[k];
    }
  }
}

// -------- horizontal 51-tap blur (zero padding), 4 outputs/thread --------
__global__ __launch_bounds__(256)
void blur_h_kernel(const float* __restrict__ Sin, float* __restrict__ D)
{
  __shared__ __align__(16) float row[1080];   // [-25, 1024+25) padded
  const int img = blockIdx.y;
  const int y = blockIdx.x;
  const int tid = threadIdx.x;
  const float* src = Sin + (size_t)img*HW + (size_t)y*W;
  for (int i = tid; i < 1080; i += 256) {
    int x = i - BORDER;
    row[i] = (x >= 0 && x < W) ? src[x] : 0.0f;
  }
  __syncthreads();
  const int x0 = tid * 4;
  float a0=0.f, a1=0.f, a2=0.f, a3=0.f;
  const float4* rp = (const float4*)row;
#define ACCUM(val, idx)                                                     \
  { if ((idx)   >= 0 && (idx)   <= 50) a0 += (val) * GW[(idx)];             \
    if ((idx)-1 >= 0 && (idx)-1 <= 50) a1 += (val) * GW[(idx)-1];           \
    if ((idx)-2 >= 0 && (idx)-2 <= 50) a2 += (val) * GW[(idx)-2];           \
    if ((idx)-3 >= 0 && (idx)-3 <= 50) a3 += (val) * GW[(idx)-3]; }
  #pragma unroll
  for (int t4 = 0; t4 < 14; ++t4) {
    float4 v = rp[tid + t4];
    const int base = 4*t4;
    ACCUM(v.x, base+0) ACCUM(v.y, base+1) ACCUM(v.z, base+2) ACCUM(v.w, base+3)
  }
#undef ACCUM
  float4 outv; outv.x=a0; outv.y=a1; outv.z=a2; outv.w=a3;
  *(float4*)(D + (size_t)img*HW + (size_t)y*W + x0) = outv;
}

// -------- vertical 51-tap blur + clip + soft-dice partial sums (gt,pr pair) --------
#define VTW 64
#define VTH 64
#define VLH (VTH + 2*BORDER)   // 114
__global__ __launch_bounds__(256)
void blur_v_dice_kernel(const float* __restrict__ D, double* __restrict__ sums)
{
  __shared__ float gts[VLH*VTW];
  __shared__ float prs[VLH*VTW];
  __shared__ double rbuf[12];
  const int b = blockIdx.z;
  const int gy0 = blockIdx.y * VTH;
  const int gx0 = blockIdx.x * VTW;
  const int tid = threadIdx.x;
  const float* gsrc = D + (size_t)b*HW;
  const float* psrc = D + (size_t)(b+NB)*HW;
  for (int i = tid; i < VLH*VTW; i += 256) {
    int r = i >> 6, c = i & 63;
    int gy = gy0 - BORDER + r;
    float gv = 0.f, pv = 0.f;
    if (gy >= 0 && gy < H) { int a = gy*W + gx0 + c; gv = gsrc[a]; pv = psrc[a]; }
    gts[i] = gv; prs[i] = pv;
  }
  __syncthreads();
  const int c  = tid & 63;
  const int r0 = (tid >> 6) * 16;   // 16 consecutive output rows per thread
  float ag[16], ap[16];
  #pragma unroll
  for (int j = 0; j < 16; ++j) { ag[j] = 0.f; ap[j] = 0.f; }
  #pragma unroll
  for (int t = 0; t < 16 + KLEN - 1; ++t) {   // sliding reuse: 66 loads -> 16*51 FMAs
    float vg = gts[(r0 + t)*VTW + c];
    float vp = prs[(r0 + t)*VTW + c];
    #pragma unroll
    for (int j = 0; j < 16; ++j) {
      int k = t - j;
      if (k >= 0 && k < KLEN) { ag[j] += vg * GW[k]; ap[j] += vp * GW[k]; }
    }
  }
  double sgp = 0.0, sgg = 0.0, spp = 0.0;
  #pragma unroll
  for (int j = 0; j < 16; ++j) {
    float a = fminf(fmaxf(ag[j], 0.f), 1.f);
    float p = fminf(fmaxf(ap[j], 0.f), 1.f);
    sgp += (double)(a*p); sgg += (double)(a*a); spp += (double)(p*p);
  }
  #pragma unroll
  for (int off = 32; off > 0; off >>= 1) {
    sgp += __shfl_down(sgp, off);
    sgg += __shfl_down(sgg, off);
    spp += __shfl_down(spp, off);
  }
  int lane = tid & 63, wv = tid >> 6;
  if (lane == 0) { rbuf[wv] = sgp; rbuf[4+wv] = sgg; rbuf[8+wv] = spp; }
  __syncthreads();
  if (tid == 0) {
    double a  = rbuf[0]+rbuf[1]+rbuf[2]+rbuf[3];
    double g2 = rbuf[4]+rbuf[5]+rbuf[6]+rbuf[7];
    double p2 = rbuf[8]+rbuf[9]+rbuf[10]+rbuf[11];
    atomicAdd(&sums[b],        a);
    atomicAdd(&sums[NB+b],     g2);
    atomicAdd(&sums[2*NB+b],   p2);
  }
}

__global__ void final_kernel(const double* __restrict__ sums, float* __restrict__ out) {
  if (threadIdx.x == 0) {
    double acc = 0.0;
    for (int b = 0; b < NB; ++b) {
      double num = 2.0*sums[b] + 1e-6;
      double den = sums[NB+b] + sums[2*NB+b] + 1e-6;
      acc += 1.0 - num/den;
    }
    out[0] = (float)(acc / (double)NB);
  }
}

extern "C" void kernel_launch(void* const* d_in, const int* in_sizes, int n_in,
                              void* d_out, int out_size, void* d_ws, size_t ws_size,
                              hipStream_t stream)
{
  (void)in_sizes; (void)n_in; (void)out_size; (void)ws_size;
  const float* pred = (const float*)d_in[0];   // (8,2,1024,1024) f32
  const float* targ = (const float*)d_in[1];   // (8,1024,1024) f32
  float* out = (float*)d_out;

  float* Ybuf = (float*)d_ws;                        // 16*HW floats (blur tmp)
  float* Sbuf = Ybuf + (size_t)NIMG*HW;              // 16*HW floats (skel)
  double* sums = (double*)(Sbuf + (size_t)NIMG*HW);  // 24 doubles

  // all 11 skeletonize units in one launch (center 104x72 per block); zeroes sums
  hipLaunchKernelGGL(skel11_kernel, dim3(10, 15, NIMG), dim3(512), 0, stream,
                     pred, targ, Sbuf, sums);
  // Gaussian border: horizontal then vertical(+dice partial sums)
  hipLaunchKernelGGL(blur_h_kernel, dim3(H, NIMG), dim3(256), 0, stream, Sbuf, Ybuf);
  hipLaunchKernelGGL(blur_v_dice_kernel, dim3(W/VTW, H/VTH, NB), dim3(256), 0, stream, Ybuf, sums);
  hipLaunchKernelGGL(final_kernel, dim3(1), dim3(64), 0, stream, sums, out);
}

// Round 8
// 219.851 us; speedup vs baseline: 4.6863x; 1.1550x over previous
//
#include <hip/hip_runtime.h>

// ---------------- problem constants ----------------
#define H 1024
#define W 1024
#define HW (H*W)
#define NB 8            // batch
#define NIMG 16         // gt batch (0..7) + pred-fg batch (8..15)
#define BORDER 25
#define KLEN 51

// Unnormalized Gaussian weights g[k] = exp(-(k-25)^2/200), k=0..50 (sigma=10).
__device__ __constant__ float GW[KLEN] = {
  0.04393693f, 0.05613476f, 0.07100535f, 0.08892162f, 0.11025053f,
  0.13533528f, 0.16447446f, 0.19789869f, 0.23574608f, 0.27803730f,
  0.32465247f, 0.37531110f, 0.42955736f, 0.48675226f, 0.54607442f,
  0.60653066f, 0.66697681f, 0.72614904f, 0.78270454f, 0.83527021f,
  0.88249690f, 0.92311635f, 0.95599748f, 0.98019867f, 0.99501248f,
  1.00000000f,
  0.99501248f, 0.98019867f, 0.95599748f, 0.92311635f, 0.88249690f,
  0.83527021f, 0.78270454f, 0.72614904f, 0.66697681f, 0.60653066f,
  0.54607442f, 0.48675226f, 0.42955736f, 0.37531110f, 0.32465247f,
  0.27803730f, 0.23574608f, 0.19789869f, 0.16447446f, 0.13533528f,
  0.11025053f, 0.08892162f, 0.07100535f, 0.05613476f, 0.04393693f
};

// Force single-instruction 3-input min/max (VOP3; all operands VGPR).
__device__ inline float m3n(float a,float b,float c){
  float d; asm("v_min3_f32 %0, %1, %2, %3" : "=v"(d) : "v"(a), "v"(b), "v"(c));
  return d;
}
__device__ inline float m3x(float a,float b,float c){
  float d; asm("v_max3_f32 %0, %1, %2, %3" : "=v"(d) : "v"(a), "v"(b), "v"(c));
  return d;
}

// Single-inst DPP wave shifts (bound_ctrl: OOB lane -> 0). The zeroed lane only
// corrupts buffer col 0 / col 127 — already invalid halo (12px budget).
__device__ inline float dpp_shr1(float x){   // lane i <- lane i-1
  return __int_as_float(__builtin_amdgcn_mov_dpp(__float_as_int(x), 0x138, 0xf, 0xf, true));
}
__device__ inline float dpp_shl1(float x){   // lane i <- lane i+1
  return __int_as_float(__builtin_amdgcn_mov_dpp(__float_as_int(x), 0x130, 0xf, 0xf, true));
}

__device__ inline float4 hmin4(float4 C){
  float Lw = dpp_shr1(C.w);
  float Rx = dpp_shl1(C.x);
  float4 h;
  h.x=m3n(Lw ,C.x,C.y); h.y=m3n(C.x,C.y,C.z);
  h.z=m3n(C.y,C.z,C.w); h.w=m3n(C.z,C.w,Rx );
  return h;
}
__device__ inline float4 hmax4(float4 C){
  float Lw = dpp_shr1(C.w);
  float Rx = dpp_shl1(C.x);
  float4 h;
  h.x=m3x(Lw ,C.x,C.y); h.y=m3x(C.x,C.y,C.z);
  h.z=m3x(C.y,C.z,C.w); h.w=m3x(C.z,C.w,Rx );
  return h;
}
__device__ inline float4 vmin3(float4 a,float4 b,float4 c){
  float4 o; o.x=m3n(a.x,b.x,c.x); o.y=m3n(a.y,b.y,c.y);
            o.z=m3n(a.z,b.z,c.z); o.w=m3n(a.w,b.w,c.w); return o;
}
__device__ inline float4 vmax3(float4 a,float4 b,float4 c){
  float4 o; o.x=m3x(a.x,b.x,c.x); o.y=m3x(a.y,b.y,c.y);
            o.z=m3x(a.z,b.z,c.z); o.w=m3x(a.w,b.w,c.w); return o;
}
__device__ inline float4 msk4(float4 e, bool v){
  constexpr float NINF = -__builtin_huge_valf();
  float4 o; o.x=v?e.x:NINF; o.y=v?e.y:NINF; o.z=v?e.z:NINF; o.w=v?e.w:NINF;
  return o;
}

// Single-launch register-resident fused skeletonize: all 11 units (unrolled).
// Buffer: 32 f4 (128 px) x 96 rows; center px/rows [12,116)x[12,84) -> 104x72.
// 512 threads = 16 groups x 32 lanes; group g owns rows [6g, 6g+6) in regs.
// Waves 1-6 own exactly the center rows [12,84): only they run dilate/delta/
// skel-update; waves 0/7 contribute just the boundary dilate row neighbors read.
// Exchange reads use clamped indices (clamped slot == fallback value).
// Unit u: I_{u+1}=erode(I_u); delta=relu(I_u - dilate(mask(I_{u+1})));
// s += relu(d - s*d) (s=d at u=0). +inf padding == valid-only min; mask makes
// dilate valid-only (exact vs reference). 11 erodes + 1 dilate = 12 px <= halo 12.
__global__ __launch_bounds__(512, 4)
void skel11_kernel(const float* __restrict__ pred, const float* __restrict__ targ,
                   float* __restrict__ S, double* __restrict__ sums)
{
  constexpr float PINF = __builtin_huge_valf();
  __shared__ float4 Xch[2][32][32];   // [slot][2 boundary rows x 16 groups][f4 col]

  const int img = blockIdx.z;
  const int bx = blockIdx.x, by = blockIdx.y;

  // fold zero_sums launch into this kernel (sums consumed only by later kernels)
  if (bx==0 && by==0 && img==0 && threadIdx.x < 3*NB) sums[threadIdx.x] = 0.0;

  const int gx0 = bx*104 - 12, gy0 = by*72 - 12;
  const int tid = threadIdx.x;
  const int g = tid >> 5;             // 16 row-groups
  const int j = tid & 31;             // f4-col
  const int wid = tid >> 6;           // wave 0..7
  const int R0 = 6*g;
  const int gxb = gx0 + 4*j;
  const bool xok = ((unsigned)gxb < (unsigned)W);
  const bool cenj = (j >= 3) && (j < 29);
  const bool allok = (gx0 >= 0) && (gx0 + 128 <= W) && (gy0 >= 0) && (gy0 + 96 <= H);
  const bool cwave = (wid >= 1) && (wid <= 6);   // rows 6g+k all in [12,84)

  // clamped exchange indices (clamped slot == own boundary row == fallback)
  const int ixm = (g>0)  ? 2*g-1 : 0;
  const int ixp = (g<15) ? 2*g+2 : 31;

  float4 I[6], s[6];
  bool yok[6];

  // ---- load 6 rows (OOB = +inf, the min identity); softmax fg for imgs 8-15 ----
  #pragma unroll
  for (int k=0;k<6;++k) {
    int gy = gy0 + R0 + k;
    yok[k] = ((unsigned)gy < (unsigned)H);
    float4 v = make_float4(PINF,PINF,PINF,PINF);
    if (yok[k] && xok) {
      size_t off = (size_t)gy*(W/4) + (gxb>>2);
      if (img < NB) {
        v = ((const float4*)targ)[(size_t)img*(HW/4)+off];
      } else {
        int b2 = img - NB;
        float4 p0 = ((const float4*)pred)[(size_t)(2*b2  )*(HW/4)+off];
        float4 p1 = ((const float4*)pred)[(size_t)(2*b2+1)*(HW/4)+off];
        v.x = 1.0f/(1.0f + expf(p0.x - p1.x));
        v.y = 1.0f/(1.0f + expf(p0.y - p1.y));
        v.z = 1.0f/(1.0f + expf(p0.z - p1.z));
        v.w = 1.0f/(1.0f + expf(p0.w - p1.w));
      }
    }
    I[k] = v;
  }

  #pragma unroll
  for (int u=0; u<11; ++u) {
    // ---- erode (all waves): H-min via DPP; V-min with boundary exchange ----
    float4 h[6];
    #pragma unroll
    for (int k=0;k<6;++k) h[k] = hmin4(I[k]);
    Xch[0][2*g  ][j] = h[0];
    Xch[0][2*g+1][j] = h[5];
    __syncthreads();
    float4 hm = Xch[0][ixm][j];
    float4 hp = Xch[0][ixp][j];
    float4 e[6];
    e[0]=vmin3(hm  ,h[0],h[1]);
    e[1]=vmin3(h[0],h[1],h[2]);
    e[2]=vmin3(h[1],h[2],h[3]);
    e[3]=vmin3(h[2],h[3],h[4]);
    e[4]=vmin3(h[3],h[4],h[5]);
    e[5]=vmin3(h[4],h[5],hp  );

    // ---- dilate of masked I_{u+1}: full on waves 1-6, boundary row on 0/7 ----
    float4 x[6];
    if (cwave) {
      if (allok) {
        #pragma unroll
        for (int k=0;k<6;++k) x[k] = hmax4(e[k]);
      } else {
        #pragma unroll
        for (int k=0;k<6;++k) x[k] = hmax4(msk4(e[k], xok && yok[k]));
      }
      Xch[1][2*g  ][j] = x[0];
      Xch[1][2*g+1][j] = x[5];
    } else if (wid == 0) {      // neighbors read only group1 row5 (Xch[1][3])
      float4 x5 = allok ? hmax4(e[5]) : hmax4(msk4(e[5], xok && yok[5]));
      Xch[1][2*g+1][j] = x5;
    } else {                    // wid==7: neighbors read only group14 row0 (Xch[1][28])
      float4 x0 = allok ? hmax4(e[0]) : hmax4(msk4(e[0], xok && yok[0]));
      Xch[1][2*g  ][j] = x0;
    }
    __syncthreads();

    // ---- delta + skel update (waves 1-6 only; their rows are all center) ----
    if (cwave) {
      float4 xm = Xch[1][2*g-1][j];   // g in [2,13]: indices always valid
      float4 xp = Xch[1][2*g+2][j];
      #pragma unroll
      for (int k=0;k<6;++k) {
        float4 dl = vmax3((k==0)?xm:x[k-1], x[k], (k==5)?xp:x[k+1]);
        float dx = fmaxf(I[k].x-dl.x,0.f), dy = fmaxf(I[k].y-dl.y,0.f);
        float dz = fmaxf(I[k].z-dl.z,0.f), dw = fmaxf(I[k].w-dl.w,0.f);
        if (u == 0) {
          s[k] = make_float4(dx,dy,dz,dw);
        } else {
          s[k].x += fmaxf(fmaf(-s[k].x, dx, dx), 0.f);
          s[k].y += fmaxf(fmaf(-s[k].y, dy, dy), 0.f);
          s[k].z += fmaxf(fmaf(-s[k].z, dz, dz), 0.f);
          s[k].w += fmaxf(fmaf(-s[k].w, dw, dw), 0.f);
        }
      }
    }
    #pragma unroll
    for (int k=0;k<6;++k) I[k] = e[k];
  }

  // ---- write back skel (waves 1-6, center cols, clipped to image) ----
  if (cwave && cenj && gxb < W) {
    #pragma unroll
    for (int k=0;k<6;++k) {
      int gy = gy0 + R0 + k;        // rows 12..83 of buffer -> gy >= 0
      if (gy < H)
        ((float4*)S)[(size_t)img*(HW/4) + (size_t)gy*(W/4) + (gxb>>2)] = s[k];
    }
  }
}

// -------- horizontal 51-tap blur (zero padding), LDS-free --------
// One block per row; thread q computes output f4 q from 15 overlapping f4
// global loads (L1-cached stencil, fully coalesced per wave).
__global__ __launch_bounds__(256)
void blur_h_kernel(const float* __restrict__ Sin, float* __restrict__ D)
{
  const int img = blockIdx.y;
  const int y = blockIdx.x;
  const int q = threadIdx.x;                 // output f4 index 0..255
  const float4* src = (const float4*)(Sin + (size_t)img*HW + (size_t)y*W);
  float a0=0.f, a1=0.f, a2=0.f, a3=0.f;
#define ACCUM(val, idx)                                                     \
  { if ((idx)   >= 0 && (idx)   <= 50) a0 += (val) * GW[(idx)];             \
    if ((idx)-1 >= 0 && (idx)-1 <= 50) a1 += (val) * GW[(idx)-1];           \
    if ((idx)-2 >= 0 && (idx)-2 <= 50) a2 += (val) * GW[(idx)-2];           \
    if ((idx)-3 >= 0 && (idx)-3 <= 50) a3 += (val) * GW[(idx)-3]; }
  #pragma unroll
  for (int c = -7; c <= 7; ++c) {
    int qq = q + c;
    float4 v = make_float4(0.f,0.f,0.f,0.f);
    if ((unsigned)qq < 256u) v = src[qq];
    const int base = 4*c + 25;               // tap idx of v.x for output px 4q
    ACCUM(v.x, base+0) ACCUM(v.y, base+1) ACCUM(v.z, base+2) ACCUM(v.w, base+3)
  }
#undef ACCUM
  float4 outv; outv.x=a0; outv.y=a1; outv.z=a2; outv.w=a3;
  ((float4*)(D + (size_t)img*HW + (size_t)y*W))[q] = outv;
}

// -------- vertical 51-tap blur + clip + soft-dice partial sums, LDS-free ----
// Thread owns one column x 16 output rows; 66 wave-coalesced global loads
// (256B/load) slide through a 16-acc register window. Halo rows L2-warm.
__global__ __launch_bounds__(256)
void blur_v_dice_kernel(const float* __restrict__ D, double* __restrict__ sums)
{
  __shared__ double rbuf[12];
  const int b = blockIdx.z;
  const int gy0 = blockIdx.y * 64;
  const int gx0 = blockIdx.x * 64;
  const int tid = threadIdx.x;
  const int c  = tid & 63;
  const int r0 = gy0 + (tid >> 6) * 16;      // 16 consecutive output rows
  const int x  = gx0 + c;
  const float* gsrc = D + (size_t)b*HW + x;
  const float* psrc = D + (size_t)(b+NB)*HW + x;

  float ag[16], ap[16];
  #pragma unroll
  for (int j = 0; j < 16; ++j) { ag[j] = 0.f; ap[j] = 0.f; }
  #pragma unroll
  for (int t = 0; t < 16 + KLEN - 1; ++t) {  // 66 loads -> 16*51 FMAs per image
    int gy = r0 - BORDER + t;
    float vg = 0.f, vp = 0.f;
    if ((unsigned)gy < (unsigned)H) {
      size_t a = (size_t)gy*W;
      vg = gsrc[a]; vp = psrc[a];
    }
    #pragma unroll
    for (int j = 0; j < 16; ++j) {
      int k = t - j;
      if (k >= 0 && k < KLEN) { ag[j] += vg * GW[k]; ap[j] += vp * GW[k]; }
    }
  }
  double sgp = 0.0, sgg = 0.0, spp = 0.0;
  #pragma unroll
  for (int j = 0; j < 16; ++j) {
    float a = fminf(fmaxf(ag[j], 0.f), 1.f);
    float p = fminf(fmaxf(ap[j], 0.f), 1.f);
    sgp += (double)(a*p); sgg += (double)(a*a); spp += (double)(p*p);
  }
  #pragma unroll
  for (int off = 32; off > 0; off >>= 1) {
    sgp += __shfl_down(sgp, off);
    sgg += __shfl_down(sgg, off);
    spp += __shfl_down(spp, off);
  }
  int lane = tid & 63, wv = tid >> 6;
  if (lane == 0) { rbuf[wv] = sgp; rbuf[4+wv] = sgg; rbuf[8+wv] = spp; }
  __syncthreads();
  if (tid == 0) {
    double a  = rbuf[0]+rbuf[1]+rbuf[2]+rbuf[3];
    double g2 = rbuf[4]+rbuf[5]+rbuf[6]+rbuf[7];
    double p2 = rbuf[8]+rbuf[9]+rbuf[10]+rbuf[11];
    atomicAdd(&sums[b],        a);
    atomicAdd(&sums[NB+b],     g2);
    atomicAdd(&sums[2*NB+b],   p2);
  }
}

__global__ void final_kernel(const double* __restrict__ sums, float* __restrict__ out) {
  if (threadIdx.x == 0) {
    double acc = 0.0;
    for (int b = 0; b < NB; ++b) {
      double num = 2.0*sums[b] + 1e-6;
      double den = sums[NB+b] + sums[2*NB+b] + 1e-6;
      acc += 1.0 - num/den;
    }
    out[0] = (float)(acc / (double)NB);
  }
}

extern "C" void kernel_launch(void* const* d_in, const int* in_sizes, int n_in,
                              void* d_out, int out_size, void* d_ws, size_t ws_size,
                              hipStream_t stream)
{
  (void)in_sizes; (void)n_in; (void)out_size; (void)ws_size;
  const float* pred = (const float*)d_in[0];   // (8,2,1024,1024) f32
  const float* targ = (const float*)d_in[1];   // (8,1024,1024) f32
  float* out = (float*)d_out;

  float* Ybuf = (float*)d_ws;                        // 16*HW floats (blur tmp)
  float* Sbuf = Ybuf + (size_t)NIMG*HW;              // 16*HW floats (skel)
  double* sums = (double*)(Sbuf + (size_t)NIMG*HW);  // 24 doubles

  // all 11 skeletonize units in one launch (center 104x72 per block); zeroes sums
  hipLaunchKernelGGL(skel11_kernel, dim3(10, 15, NIMG), dim3(512), 0, stream,
                     pred, targ, Sbuf, sums);
  // Gaussian border: horizontal then vertical(+dice partial sums)
  hipLaunchKernelGGL(blur_h_kernel, dim3(H, NIMG), dim3(256), 0, stream, Sbuf, Ybuf);
  hipLaunchKernelGGL(blur_v_dice_kernel, dim3(W/64, H/64, NB), dim3(256), 0, stream, Ybuf, sums);
  hipLaunchKernelGGL(final_kernel, dim3(1), dim3(64), 0, stream, sums, out);
}